// Round 1
// baseline (1541.046 us; speedup 1.0000x reference)
//
#include <hip/hip_runtime.h>

// FuncConv: out = select(inv, mlp_inv(res), res); res = mlp_and(mean_dst(msg));
// msg = select(r, mlp_inv(feat[src]), feat[src]).
// Strategy: precompute inv_feat = mlp_inv(feat) over nodes (4x fewer FLOPs than
// per-edge), f32-atomic scatter-mean, then two more MLP passes.
// MLPs run on bf16 MFMA (16x16x32), f32 accum. Threshold is bf16-grade.
//
// ws layout (floats): [0, N*H)        inv_feat   (later reused for res)
//                     [N*H, 2*N*H)    neigh_sum
//                     [2*N*H, +N)     deg
// needs (2*N*H + N)*4 ~= 103 MB of ws.

#define H 128
#define HH 64

typedef float f32x4 __attribute__((ext_vector_type(4)));
typedef __bf16 bf16x8 __attribute__((ext_vector_type(8)));
typedef unsigned short us8 __attribute__((ext_vector_type(8)));

__device__ __forceinline__ unsigned short bfbits(float f) {
    __bf16 h = (__bf16)f;                       // RNE convert
    return __builtin_bit_cast(unsigned short, h);
}
__device__ __forceinline__ bf16x8 as_bf16x8(us8 v) {
    return __builtin_bit_cast(bf16x8, v);
}

// per-wave transpose buffer: 16 rows x 64 cols bf16, XOR-swizzled
// (row stride 128B; swizzle byte ^= (row&7)<<4 keeps 16B reads conflict-light)
__device__ __forceinline__ int tb_off(int m, int j) {
    return m * 64 + ((((j * 2) ^ ((m & 7) << 4))) >> 1);
}
__device__ __forceinline__ bf16x8 ld_tb(const unsigned short* tb, int m, int j0) {
    return as_bf16x8(*(const us8*)&tb[tb_off(m, j0)]);
}
__device__ __forceinline__ bf16x8 ld_fr(const unsigned short* FR, int fid, int lane) {
    return as_bf16x8(*(const us8*)&FR[(fid * 64 + lane) * 8]);
}

// Fused 3-layer MLP over rows of X (Linear->LReLU->Linear->LReLU->Linear).
// deg!=null : scale each input row by 1/max(deg,1)   (mean aggregation)
// inv!=null : out = inv ? mlp(x) : x                 (final select)
// One wave computes a 16-row tile. 4 waves/block. Weights pre-packed as
// MFMA B-fragments in LDS (B[k][n] = w[n][k]; lane: n=lane&15, k=(lane>>4)*8+e).
__global__ __launch_bounds__(256) void mlp3_rows(
    const float* __restrict__ X,
    const float* __restrict__ W1, const float* __restrict__ B1,
    const float* __restrict__ W2, const float* __restrict__ B2,
    const float* __restrict__ W3, const float* __restrict__ B3,
    float* __restrict__ OUT,
    const float* __restrict__ deg,
    const int* __restrict__ inv,
    int nrows)
{
    // frag ids: [0,16) = W1 (s=fid>>2, t=fid&3), [16,24) = W2, [24,40) = W3
    __shared__ __align__(16) unsigned short FR[40 * 64 * 8];   // 40 KB
    __shared__ __align__(16) unsigned short TBs[4 * 16 * 64];  // 8 KB
    const int tid  = threadIdx.x;
    const int wv   = tid >> 6;
    const int lane = tid & 63;
    const int ln   = lane & 15;
    const int hi   = lane >> 4;

    for (int fid = wv; fid < 40; fid += 4) {
        const float* w; int inF, s, t;
        if (fid < 16)      { w = W1; inF = H;  s = fid >> 2;        t = fid & 3; }
        else if (fid < 24) { w = W2; inF = HH; s = (fid - 16) >> 2; t = (fid - 16) & 3; }
        else               { w = W3; inF = HH; s = (fid - 24) >> 3; t = (fid - 24) & 7; }
        const float* p = w + (size_t)(t * 16 + ln) * inF + (s * 32 + hi * 8);
        f32x4 a = *(const f32x4*)p;
        f32x4 b = *(const f32x4*)(p + 4);
        unsigned short* d = &FR[(fid * 64 + lane) * 8];
        d[0] = bfbits(a[0]); d[1] = bfbits(a[1]); d[2] = bfbits(a[2]); d[3] = bfbits(a[3]);
        d[4] = bfbits(b[0]); d[5] = bfbits(b[1]); d[6] = bfbits(b[2]); d[7] = bfbits(b[3]);
    }
    __syncthreads();

    const int tile = blockIdx.x * 4 + wv;
    if (tile * 16 >= nrows) return;
    const int node0 = tile * 16;
    unsigned short* tb = &TBs[wv * 16 * 64];

    // ---- A1 fragments from global (f32 -> bf16), optional 1/deg scaling
    const int arow = min(node0 + ln, nrows - 1);
    float sc = 1.0f;
    if (deg) sc = 1.0f / fmaxf(deg[arow], 1.0f);
    const float* xr = X + (size_t)arow * H;
    bf16x8 a1[4];
#pragma unroll
    for (int s = 0; s < 4; ++s) {
        f32x4 u = *(const f32x4*)(xr + s * 32 + hi * 8);
        f32x4 v = *(const f32x4*)(xr + s * 32 + hi * 8 + 4);
        bf16x8 f;
        f[0] = (__bf16)(u[0] * sc); f[1] = (__bf16)(u[1] * sc);
        f[2] = (__bf16)(u[2] * sc); f[3] = (__bf16)(u[3] * sc);
        f[4] = (__bf16)(v[0] * sc); f[5] = (__bf16)(v[1] * sc);
        f[6] = (__bf16)(v[2] * sc); f[7] = (__bf16)(v[3] * sc);
        a1[s] = f;
    }

    // ---- layer 1: Y1[16x64] = X[16x128] * W1^T + b1, LReLU -> TB
#pragma unroll
    for (int t = 0; t < 4; ++t) {
        f32x4 acc = {0.f, 0.f, 0.f, 0.f};
#pragma unroll
        for (int s = 0; s < 4; ++s)
            acc = __builtin_amdgcn_mfma_f32_16x16x32_bf16(a1[s], ld_fr(FR, s * 4 + t, lane), acc, 0, 0, 0);
        const float bb = B1[t * 16 + ln];
#pragma unroll
        for (int q = 0; q < 4; ++q) {
            float y = acc[q] + bb;
            y = (y >= 0.f) ? y : 0.01f * y;
            tb[tb_off(hi * 4 + q, t * 16 + ln)] = bfbits(y);   // D: row=hi*4+q, col=ln
        }
    }

    // ---- layer 2: Y2[16x64] = Y1 * W2^T + b2, LReLU -> TB
    bf16x8 a2[2];
#pragma unroll
    for (int s = 0; s < 2; ++s) a2[s] = ld_tb(tb, ln, s * 32 + hi * 8);
#pragma unroll
    for (int t = 0; t < 4; ++t) {
        f32x4 acc = {0.f, 0.f, 0.f, 0.f};
#pragma unroll
        for (int s = 0; s < 2; ++s)
            acc = __builtin_amdgcn_mfma_f32_16x16x32_bf16(a2[s], ld_fr(FR, 16 + s * 4 + t, lane), acc, 0, 0, 0);
        const float bb = B2[t * 16 + ln];
#pragma unroll
        for (int q = 0; q < 4; ++q) {
            float y = acc[q] + bb;
            y = (y >= 0.f) ? y : 0.01f * y;
            tb[tb_off(hi * 4 + q, t * 16 + ln)] = bfbits(y);
        }
    }

    // ---- layer 3: OUT[16x128] = Y2 * W3^T + b3 (no activation)
    bf16x8 a3[2];
#pragma unroll
    for (int s = 0; s < 2; ++s) a3[s] = ld_tb(tb, ln, s * 32 + hi * 8);
    int ivr[4] = {0, 0, 0, 0};
    if (inv) {
#pragma unroll
        for (int q = 0; q < 4; ++q) ivr[q] = inv[min(node0 + hi * 4 + q, nrows - 1)];
    }
#pragma unroll
    for (int t = 0; t < 8; ++t) {
        f32x4 acc = {0.f, 0.f, 0.f, 0.f};
#pragma unroll
        for (int s = 0; s < 2; ++s)
            acc = __builtin_amdgcn_mfma_f32_16x16x32_bf16(a3[s], ld_fr(FR, 24 + s * 8 + t, lane), acc, 0, 0, 0);
        const float bb = B3[t * 16 + ln];
#pragma unroll
        for (int q = 0; q < 4; ++q) {
            const int m   = hi * 4 + q;
            const int row = node0 + m;
            if (row < nrows) {
                const int col = t * 16 + ln;
                float y = acc[q] + bb;
                if (inv && !ivr[q]) y = X[(size_t)row * H + col];  // exact f32 passthrough
                OUT[(size_t)row * H + col] = y;
            }
        }
    }
}

// Per edge: 32 threads x float4 each; gather msg row, atomic-scatter into
// neigh_sum[dst], thread q==0 bumps deg[dst].
__global__ __launch_bounds__(256) void edge_scatter(
    const float* __restrict__ feat, const float* __restrict__ inv_feat,
    const int* __restrict__ src, const int* __restrict__ dst, const int* __restrict__ r,
    float* __restrict__ neigh, float* __restrict__ deg, int E)
{
    const int tid = blockIdx.x * blockDim.x + threadIdx.x;
    const int e = tid >> 5;
    if (e >= E) return;
    const int q = tid & 31;
    const int s = src[e];
    const int d = dst[e];
    const float* base = (r[e] ? inv_feat : feat) + (size_t)s * H + q * 4;
    f32x4 v = *(const f32x4*)base;
    float* o = neigh + (size_t)d * H + q * 4;
    atomicAdd(o + 0, v[0]);
    atomicAdd(o + 1, v[1]);
    atomicAdd(o + 2, v[2]);
    atomicAdd(o + 3, v[3]);
    if (q == 0) atomicAdd(deg + d, 1.0f);
}

extern "C" void kernel_launch(void* const* d_in, const int* in_sizes, int n_in,
                              void* d_out, int out_size, void* d_ws, size_t ws_size,
                              hipStream_t stream) {
    const float* feat = (const float*)d_in[0];
    const int*   src  = (const int*)d_in[1];
    const int*   dst  = (const int*)d_in[2];
    const int*   r    = (const int*)d_in[3];
    const int*   inv  = (const int*)d_in[4];
    const float* iw1 = (const float*)d_in[5],  *ib1 = (const float*)d_in[6];
    const float* iw2 = (const float*)d_in[7],  *ib2 = (const float*)d_in[8];
    const float* iw3 = (const float*)d_in[9],  *ib3 = (const float*)d_in[10];
    const float* aw1 = (const float*)d_in[11], *ab1 = (const float*)d_in[12];
    const float* aw2 = (const float*)d_in[13], *ab2 = (const float*)d_in[14];
    const float* aw3 = (const float*)d_in[15], *ab3 = (const float*)d_in[16];

    const int N = in_sizes[4];   // inv is [N]
    const int E = in_sizes[1];   // src is [E]

    float* ws       = (float*)d_ws;
    float* inv_feat = ws;                          // N*H f32 (reused as res later)
    float* neigh    = ws + (size_t)N * H;          // N*H f32
    float* degb     = ws + (size_t)2 * N * H;      // N f32

    hipMemsetAsync(neigh, 0, ((size_t)N * H + N) * sizeof(float), stream);

    const int ntiles = (N + 15) / 16;
    const int nblk   = (ntiles + 3) / 4;

    // 1) inv_feat = mlp_inv(feat) over all nodes
    mlp3_rows<<<nblk, 256, 0, stream>>>(feat, iw1, ib1, iw2, ib2, iw3, ib3,
                                        inv_feat, nullptr, nullptr, N);
    // 2) scatter-mean messages
    const int eb = (int)(((long long)E * 32 + 255) / 256);
    edge_scatter<<<eb, 256, 0, stream>>>(feat, inv_feat, src, dst, r, neigh, degb, E);
    // 3) res = mlp_and(neigh_sum / deg)   (res overwrites inv_feat region)
    mlp3_rows<<<nblk, 256, 0, stream>>>(neigh, aw1, ab1, aw2, ab2, aw3, ab3,
                                        inv_feat, degb, nullptr, N);
    // 4) out = inv ? mlp_inv(res) : res
    mlp3_rows<<<nblk, 256, 0, stream>>>(inv_feat, iw1, ib1, iw2, ib2, iw3, ib3,
                                        (float*)d_out, nullptr, inv, N);
}

// Round 2
// 346.322 us; speedup vs baseline: 4.4497x; 4.4497x over previous
//
#include <hip/hip_runtime.h>

// FuncConv: out = select(inv, mlp_inv(res), res); res = mlp_and(mean_dst(msg));
// msg = select(r, mlp_inv(feat[src]), feat[src]).
// R1: replace contended f32-atomic scatter-mean (1385us, 90% of runtime) with
// counting-sort CSR build + per-node gather-mean (no f32 atomics).
// MLPs run on bf16 MFMA (16x16x32), f32 accum (verified absmax 2e-3 in R0).
//
// ws layout: inv_feat[N*H f32] | neigh[N*H f32] | cnt[N] | offsets[N] |
//            cursor[N] | packed[E] | bsum[nchunks]   (~107 MB)

#define H 128
#define HH 64
#define CHUNK 2048

typedef float f32x2 __attribute__((ext_vector_type(2)));
typedef float f32x4 __attribute__((ext_vector_type(4)));
typedef __bf16 bf16x8 __attribute__((ext_vector_type(8)));
typedef unsigned short us8 __attribute__((ext_vector_type(8)));

__device__ __forceinline__ unsigned short bfbits(float f) {
    __bf16 h = (__bf16)f;                       // RNE convert
    return __builtin_bit_cast(unsigned short, h);
}
__device__ __forceinline__ bf16x8 as_bf16x8(us8 v) {
    return __builtin_bit_cast(bf16x8, v);
}

// per-wave transpose buffer: 16 rows x 64 cols bf16, XOR-swizzled
__device__ __forceinline__ int tb_off(int m, int j) {
    return m * 64 + ((((j * 2) ^ ((m & 7) << 4))) >> 1);
}
__device__ __forceinline__ bf16x8 ld_tb(const unsigned short* tb, int m, int j0) {
    return as_bf16x8(*(const us8*)&tb[tb_off(m, j0)]);
}
__device__ __forceinline__ bf16x8 ld_fr(const unsigned short* FR, int fid, int lane) {
    return as_bf16x8(*(const us8*)&FR[(fid * 64 + lane) * 8]);
}

// ---------------- fused 3-layer MLP (unchanged from R0, passed) --------------
__global__ __launch_bounds__(256) void mlp3_rows(
    const float* __restrict__ X,
    const float* __restrict__ W1, const float* __restrict__ B1,
    const float* __restrict__ W2, const float* __restrict__ B2,
    const float* __restrict__ W3, const float* __restrict__ B3,
    float* __restrict__ OUT,
    const int* __restrict__ inv,
    int nrows)
{
    __shared__ __align__(16) unsigned short FR[40 * 64 * 8];   // 40 KB
    __shared__ __align__(16) unsigned short TBs[4 * 16 * 64];  // 8 KB
    const int tid  = threadIdx.x;
    const int wv   = tid >> 6;
    const int lane = tid & 63;
    const int ln   = lane & 15;
    const int hi   = lane >> 4;

    for (int fid = wv; fid < 40; fid += 4) {
        const float* w; int inF, s, t;
        if (fid < 16)      { w = W1; inF = H;  s = fid >> 2;        t = fid & 3; }
        else if (fid < 24) { w = W2; inF = HH; s = (fid - 16) >> 2; t = (fid - 16) & 3; }
        else               { w = W3; inF = HH; s = (fid - 24) >> 3; t = (fid - 24) & 7; }
        const float* p = w + (size_t)(t * 16 + ln) * inF + (s * 32 + hi * 8);
        f32x4 a = *(const f32x4*)p;
        f32x4 b = *(const f32x4*)(p + 4);
        unsigned short* d = &FR[(fid * 64 + lane) * 8];
        d[0] = bfbits(a[0]); d[1] = bfbits(a[1]); d[2] = bfbits(a[2]); d[3] = bfbits(a[3]);
        d[4] = bfbits(b[0]); d[5] = bfbits(b[1]); d[6] = bfbits(b[2]); d[7] = bfbits(b[3]);
    }
    __syncthreads();

    const int tile = blockIdx.x * 4 + wv;
    if (tile * 16 >= nrows) return;
    const int node0 = tile * 16;
    unsigned short* tb = &TBs[wv * 16 * 64];

    const int arow = min(node0 + ln, nrows - 1);
    const float* xr = X + (size_t)arow * H;
    bf16x8 a1[4];
#pragma unroll
    for (int s = 0; s < 4; ++s) {
        f32x4 u = *(const f32x4*)(xr + s * 32 + hi * 8);
        f32x4 v = *(const f32x4*)(xr + s * 32 + hi * 8 + 4);
        bf16x8 f;
        f[0] = (__bf16)u[0]; f[1] = (__bf16)u[1]; f[2] = (__bf16)u[2]; f[3] = (__bf16)u[3];
        f[4] = (__bf16)v[0]; f[5] = (__bf16)v[1]; f[6] = (__bf16)v[2]; f[7] = (__bf16)v[3];
        a1[s] = f;
    }

#pragma unroll
    for (int t = 0; t < 4; ++t) {
        f32x4 acc = {0.f, 0.f, 0.f, 0.f};
#pragma unroll
        for (int s = 0; s < 4; ++s)
            acc = __builtin_amdgcn_mfma_f32_16x16x32_bf16(a1[s], ld_fr(FR, s * 4 + t, lane), acc, 0, 0, 0);
        const float bb = B1[t * 16 + ln];
#pragma unroll
        for (int q = 0; q < 4; ++q) {
            float y = acc[q] + bb;
            y = (y >= 0.f) ? y : 0.01f * y;
            tb[tb_off(hi * 4 + q, t * 16 + ln)] = bfbits(y);
        }
    }

    bf16x8 a2[2];
#pragma unroll
    for (int s = 0; s < 2; ++s) a2[s] = ld_tb(tb, ln, s * 32 + hi * 8);
#pragma unroll
    for (int t = 0; t < 4; ++t) {
        f32x4 acc = {0.f, 0.f, 0.f, 0.f};
#pragma unroll
        for (int s = 0; s < 2; ++s)
            acc = __builtin_amdgcn_mfma_f32_16x16x32_bf16(a2[s], ld_fr(FR, 16 + s * 4 + t, lane), acc, 0, 0, 0);
        const float bb = B2[t * 16 + ln];
#pragma unroll
        for (int q = 0; q < 4; ++q) {
            float y = acc[q] + bb;
            y = (y >= 0.f) ? y : 0.01f * y;
            tb[tb_off(hi * 4 + q, t * 16 + ln)] = bfbits(y);
        }
    }

    bf16x8 a3[2];
#pragma unroll
    for (int s = 0; s < 2; ++s) a3[s] = ld_tb(tb, ln, s * 32 + hi * 8);
    int ivr[4] = {0, 0, 0, 0};
    if (inv) {
#pragma unroll
        for (int q = 0; q < 4; ++q) ivr[q] = inv[min(node0 + hi * 4 + q, nrows - 1)];
    }
#pragma unroll
    for (int t = 0; t < 8; ++t) {
        f32x4 acc = {0.f, 0.f, 0.f, 0.f};
#pragma unroll
        for (int s = 0; s < 2; ++s)
            acc = __builtin_amdgcn_mfma_f32_16x16x32_bf16(a3[s], ld_fr(FR, 24 + s * 8 + t, lane), acc, 0, 0, 0);
        const float bb = B3[t * 16 + ln];
#pragma unroll
        for (int q = 0; q < 4; ++q) {
            const int m   = hi * 4 + q;
            const int row = node0 + m;
            if (row < nrows) {
                const int col = t * 16 + ln;
                float y = acc[q] + bb;
                if (inv && !ivr[q]) y = X[(size_t)row * H + col];
                OUT[(size_t)row * H + col] = y;
            }
        }
    }
}

// ---------------- CSR build (counting sort by dst) ---------------------------
__global__ __launch_bounds__(256) void hist_k(const int* __restrict__ dst,
                                              int* __restrict__ cnt, int E) {
    int e = blockIdx.x * 256 + threadIdx.x;
    if (e < E) atomicAdd(&cnt[dst[e]], 1);
}

__global__ __launch_bounds__(256) void scan1_k(const int* __restrict__ cnt,
                                               int* __restrict__ bsum, int N) {
    __shared__ int s[256];
    const int b = blockIdx.x, tid = threadIdx.x;
    const int base = b * CHUNK + tid * 8;
    int sum = 0;
#pragma unroll
    for (int j = 0; j < 8; ++j) { int i = base + j; if (i < N) sum += cnt[i]; }
    s[tid] = sum;
    __syncthreads();
    for (int st = 128; st > 0; st >>= 1) {
        if (tid < st) s[tid] += s[tid + st];
        __syncthreads();
    }
    if (tid == 0) bsum[b] = s[0];
}

__global__ void scan2_k(int* bsum, int nchunks) {
    if (threadIdx.x == 0 && blockIdx.x == 0) {
        int run = 0;
        for (int i = 0; i < nchunks; ++i) { int v = bsum[i]; bsum[i] = run; run += v; }
    }
}

__global__ __launch_bounds__(256) void scan3_k(const int* __restrict__ cnt,
                                               const int* __restrict__ bsum,
                                               int* __restrict__ offsets,
                                               int* __restrict__ cursor, int N) {
    __shared__ int s[256];
    const int b = blockIdx.x, tid = threadIdx.x;
    const int base = b * CHUNK + tid * 8;
    int v[8];
    int tsum = 0;
#pragma unroll
    for (int j = 0; j < 8; ++j) {
        int t = (base + j < N) ? cnt[base + j] : 0;
        v[j] = tsum;                 // exclusive within thread
        tsum += t;
    }
    s[tid] = tsum;
    __syncthreads();
    for (int st = 1; st < 256; st <<= 1) {     // inclusive Hillis-Steele
        int val = (tid >= st) ? s[tid - st] : 0;
        __syncthreads();
        s[tid] += val;
        __syncthreads();
    }
    const int texcl = s[tid] - tsum + bsum[b];
#pragma unroll
    for (int j = 0; j < 8; ++j) {
        int i = base + j;
        if (i < N) { int o = texcl + v[j]; offsets[i] = o; cursor[i] = o; }
    }
}

__global__ __launch_bounds__(256) void scatter_k(const int* __restrict__ src,
                                                 const int* __restrict__ dst,
                                                 const int* __restrict__ r,
                                                 int* __restrict__ cursor,
                                                 int* __restrict__ packed, int E) {
    int e = blockIdx.x * 256 + threadIdx.x;
    if (e >= E) return;
    int d = dst[e];
    int pos = atomicAdd(&cursor[d], 1);
    packed[pos] = src[e] | (r[e] << 31);
}

// one wave per node: 64 lanes x float2 = 128 cols; sum bucket rows, write mean
__global__ __launch_bounds__(256) void gather_mean_k(
    const float* __restrict__ feat, const float* __restrict__ inv_feat,
    const int* __restrict__ offsets, const int* __restrict__ cnt,
    const int* __restrict__ packed, float* __restrict__ neigh, int N)
{
    const int wv = threadIdx.x >> 6, lane = threadIdx.x & 63;
    const int n = blockIdx.x * 4 + wv;
    if (n >= N) return;
    const int start = offsets[n];
    const int d = cnt[n];
    f32x2 acc = {0.f, 0.f};
    for (int k = 0; k < d; ++k) {
        const int p = packed[start + k];
        const int s = p & 0x7fffffff;
        const float* base = (p < 0) ? inv_feat : feat;
        f32x2 v = *(const f32x2*)(base + (size_t)s * H + lane * 2);
        acc[0] += v[0]; acc[1] += v[1];
    }
    const float scl = 1.0f / (float)max(d, 1);
    f32x2 m = {acc[0] * scl, acc[1] * scl};
    *(f32x2*)(neigh + (size_t)n * H + lane * 2) = m;
}

extern "C" void kernel_launch(void* const* d_in, const int* in_sizes, int n_in,
                              void* d_out, int out_size, void* d_ws, size_t ws_size,
                              hipStream_t stream) {
    const float* feat = (const float*)d_in[0];
    const int*   src  = (const int*)d_in[1];
    const int*   dst  = (const int*)d_in[2];
    const int*   r    = (const int*)d_in[3];
    const int*   inv  = (const int*)d_in[4];
    const float* iw1 = (const float*)d_in[5],  *ib1 = (const float*)d_in[6];
    const float* iw2 = (const float*)d_in[7],  *ib2 = (const float*)d_in[8];
    const float* iw3 = (const float*)d_in[9],  *ib3 = (const float*)d_in[10];
    const float* aw1 = (const float*)d_in[11], *ab1 = (const float*)d_in[12];
    const float* aw2 = (const float*)d_in[13], *ab2 = (const float*)d_in[14];
    const float* aw3 = (const float*)d_in[15], *ab3 = (const float*)d_in[16];

    const int N = in_sizes[4];   // inv is [N]
    const int E = in_sizes[1];   // src is [E]

    float* inv_feat = (float*)d_ws;                 // N*H f32 (reused for res)
    float* neigh    = inv_feat + (size_t)N * H;     // N*H f32
    int*   cnt      = (int*)(neigh + (size_t)N * H);
    int*   offsets  = cnt + N;
    int*   cursor   = offsets + N;
    int*   packed   = cursor + N;
    int*   bsum     = packed + E;

    const int nchunks = (N + CHUNK - 1) / CHUNK;
    const int ntiles  = (N + 15) / 16;
    const int nblk    = (ntiles + 3) / 4;
    const int eblk    = (E + 255) / 256;

    hipMemsetAsync(cnt, 0, (size_t)N * sizeof(int), stream);

    // 1) inv_feat = mlp_inv(feat) over all nodes
    mlp3_rows<<<nblk, 256, 0, stream>>>(feat, iw1, ib1, iw2, ib2, iw3, ib3,
                                        inv_feat, nullptr, N);
    // 2) CSR build: hist -> scan -> scatter
    hist_k<<<eblk, 256, 0, stream>>>(dst, cnt, E);
    scan1_k<<<nchunks, 256, 0, stream>>>(cnt, bsum, N);
    scan2_k<<<1, 64, 0, stream>>>(bsum, nchunks);
    scan3_k<<<nchunks, 256, 0, stream>>>(cnt, bsum, offsets, cursor, N);
    scatter_k<<<eblk, 256, 0, stream>>>(src, dst, r, cursor, packed, E);
    // 3) gather-mean by dst
    gather_mean_k<<<(N + 3) / 4, 256, 0, stream>>>(feat, inv_feat, offsets, cnt,
                                                   packed, neigh, N);
    // 4) res = mlp_and(neigh)   (res overwrites inv_feat region)
    mlp3_rows<<<nblk, 256, 0, stream>>>(neigh, aw1, ab1, aw2, ab2, aw3, ab3,
                                        inv_feat, nullptr, N);
    // 5) out = inv ? mlp_inv(res) : res
    mlp3_rows<<<nblk, 256, 0, stream>>>(inv_feat, iw1, ib1, iw2, ib2, iw3, ib3,
                                        (float*)d_out, inv, N);
}

// Round 3
// 260.128 us; speedup vs baseline: 5.9242x; 1.3314x over previous
//
#include <hip/hip_runtime.h>

// FuncConv: out = select(inv, mlp_inv(res), res); res = mlp_and(mean_dst(msg));
// msg = select(r, mlp_inv(feat[src]), feat[src]).
// R2: (a) persistent grid-stride MLP blocks — stage the 80KB weight frags ONCE
//     per block instead of once per 4 tiles (was 500MB of L2 weight traffic);
// (b) bf16 gather path: feat/inv_feat stored bf16 -> gather reads halve;
// (c) neigh stored bf16 with mean folded in -> MLP-2 A-load is a raw us8 load.
//
// ws layout: [region A: N*H f32]  phase1: featb[N*H bf16] + invb[N*H bf16]
//                                 phase2 (aliased, after gather): res[N*H f32]
//            [region B: N*H bf16] neighb
//            [ints] cnt[N] offsets[N] cursor[N] packed[E] bsum[nchunks]

#define H 128
#define HH 64
#define CHUNK 2048

typedef float f32x2 __attribute__((ext_vector_type(2)));
typedef float f32x4 __attribute__((ext_vector_type(4)));
typedef __bf16 bf16x8 __attribute__((ext_vector_type(8)));
typedef unsigned short us8 __attribute__((ext_vector_type(8)));
typedef unsigned short ushort_t;

__device__ __forceinline__ unsigned short bfbits(float f) {
    __bf16 h = (__bf16)f;                       // RNE convert
    return __builtin_bit_cast(unsigned short, h);
}
__device__ __forceinline__ bf16x8 as_bf16x8(us8 v) {
    return __builtin_bit_cast(bf16x8, v);
}

// per-wave transpose buffer: 16 rows x 64 cols bf16, XOR-swizzled
__device__ __forceinline__ int tb_off(int m, int j) {
    return m * 64 + ((((j * 2) ^ ((m & 7) << 4))) >> 1);
}
__device__ __forceinline__ bf16x8 ld_tb(const unsigned short* tb, int m, int j0) {
    return as_bf16x8(*(const us8*)&tb[tb_off(m, j0)]);
}
__device__ __forceinline__ bf16x8 ld_fr(const unsigned short* FR, int fid, int lane) {
    return as_bf16x8(*(const us8*)&FR[(fid * 64 + lane) * 8]);
}

// ---------------- fused 3-layer MLP, persistent blocks -----------------------
// INB:  X is bf16 (ushort row-major), else f32
// OUTB: OUT is bf16, else f32
// WF:   also write bf16 copy of X to featb (only valid with !INB)
// SEL:  out = inv ? mlp(x) : x   (f32 passthrough from X)
template<bool INB, bool OUTB, bool WF, bool SEL>
__global__ __launch_bounds__(256) void mlp3_t(
    const void* __restrict__ X_,
    const float* __restrict__ W1, const float* __restrict__ B1,
    const float* __restrict__ W2, const float* __restrict__ B2,
    const float* __restrict__ W3, const float* __restrict__ B3,
    void* __restrict__ OUT_,
    ushort_t* __restrict__ featb,
    const int* __restrict__ inv,
    int nrows, int ntiles)
{
    __shared__ __align__(16) unsigned short FR[40 * 64 * 8];   // 40 KB
    __shared__ __align__(16) unsigned short TBs[4 * 16 * 64];  // 8 KB
    const float*    Xf   = (const float*)X_;
    const ushort_t* Xb   = (const ushort_t*)X_;
    float*          OUTf = (float*)OUT_;
    ushort_t*       OUTb = (ushort_t*)OUT_;

    const int tid  = threadIdx.x;
    const int wv   = tid >> 6;
    const int lane = tid & 63;
    const int ln   = lane & 15;
    const int hi   = lane >> 4;

    // ---- stage all weight B-fragments once per block
    for (int fid = wv; fid < 40; fid += 4) {
        const float* w; int inF, s, t;
        if (fid < 16)      { w = W1; inF = H;  s = fid >> 2;        t = fid & 3; }
        else if (fid < 24) { w = W2; inF = HH; s = (fid - 16) >> 2; t = (fid - 16) & 3; }
        else               { w = W3; inF = HH; s = (fid - 24) >> 3; t = (fid - 24) & 7; }
        const float* p = w + (size_t)(t * 16 + ln) * inF + (s * 32 + hi * 8);
        f32x4 a = *(const f32x4*)p;
        f32x4 b = *(const f32x4*)(p + 4);
        unsigned short* d = &FR[(fid * 64 + lane) * 8];
        d[0] = bfbits(a[0]); d[1] = bfbits(a[1]); d[2] = bfbits(a[2]); d[3] = bfbits(a[3]);
        d[4] = bfbits(b[0]); d[5] = bfbits(b[1]); d[6] = bfbits(b[2]); d[7] = bfbits(b[3]);
    }
    // ---- hoist biases (tile-invariant)
    float b1r[4], b2r[4], b3r[8];
#pragma unroll
    for (int t = 0; t < 4; ++t) b1r[t] = B1[t * 16 + ln];
#pragma unroll
    for (int t = 0; t < 4; ++t) b2r[t] = B2[t * 16 + ln];
#pragma unroll
    for (int t = 0; t < 8; ++t) b3r[t] = B3[t * 16 + ln];
    __syncthreads();

    unsigned short* tb = &TBs[wv * 16 * 64];

    for (int tile = blockIdx.x * 4 + wv; tile < ntiles; tile += gridDim.x * 4) {
        const int node0 = tile * 16;
        const int arow  = min(node0 + ln, nrows - 1);
        const size_t ro = (size_t)arow * H;

        bf16x8 a1[4];
#pragma unroll
        for (int s = 0; s < 4; ++s) {
            if constexpr (INB) {
                a1[s] = as_bf16x8(*(const us8*)(Xb + ro + s * 32 + hi * 8));
            } else {
                f32x4 u = *(const f32x4*)(Xf + ro + s * 32 + hi * 8);
                f32x4 v = *(const f32x4*)(Xf + ro + s * 32 + hi * 8 + 4);
                bf16x8 f;
                f[0] = (__bf16)u[0]; f[1] = (__bf16)u[1]; f[2] = (__bf16)u[2]; f[3] = (__bf16)u[3];
                f[4] = (__bf16)v[0]; f[5] = (__bf16)v[1]; f[6] = (__bf16)v[2]; f[7] = (__bf16)v[3];
                a1[s] = f;
                if constexpr (WF)
                    *(us8*)(featb + ro + s * 32 + hi * 8) = __builtin_bit_cast(us8, f);
            }
        }

        // layer 1
#pragma unroll
        for (int t = 0; t < 4; ++t) {
            f32x4 acc = {0.f, 0.f, 0.f, 0.f};
#pragma unroll
            for (int s = 0; s < 4; ++s)
                acc = __builtin_amdgcn_mfma_f32_16x16x32_bf16(a1[s], ld_fr(FR, s * 4 + t, lane), acc, 0, 0, 0);
#pragma unroll
            for (int q = 0; q < 4; ++q) {
                float y = acc[q] + b1r[t];
                y = (y >= 0.f) ? y : 0.01f * y;
                tb[tb_off(hi * 4 + q, t * 16 + ln)] = bfbits(y);
            }
        }

        // layer 2
        bf16x8 a2[2];
#pragma unroll
        for (int s = 0; s < 2; ++s) a2[s] = ld_tb(tb, ln, s * 32 + hi * 8);
#pragma unroll
        for (int t = 0; t < 4; ++t) {
            f32x4 acc = {0.f, 0.f, 0.f, 0.f};
#pragma unroll
            for (int s = 0; s < 2; ++s)
                acc = __builtin_amdgcn_mfma_f32_16x16x32_bf16(a2[s], ld_fr(FR, 16 + s * 4 + t, lane), acc, 0, 0, 0);
#pragma unroll
            for (int q = 0; q < 4; ++q) {
                float y = acc[q] + b2r[t];
                y = (y >= 0.f) ? y : 0.01f * y;
                tb[tb_off(hi * 4 + q, t * 16 + ln)] = bfbits(y);
            }
        }

        // layer 3
        bf16x8 a3[2];
#pragma unroll
        for (int s = 0; s < 2; ++s) a3[s] = ld_tb(tb, ln, s * 32 + hi * 8);
        int ivr[4] = {0, 0, 0, 0};
        if constexpr (SEL) {
#pragma unroll
            for (int q = 0; q < 4; ++q) ivr[q] = inv[min(node0 + hi * 4 + q, nrows - 1)];
        }
#pragma unroll
        for (int t = 0; t < 8; ++t) {
            f32x4 acc = {0.f, 0.f, 0.f, 0.f};
#pragma unroll
            for (int s = 0; s < 2; ++s)
                acc = __builtin_amdgcn_mfma_f32_16x16x32_bf16(a3[s], ld_fr(FR, 24 + s * 8 + t, lane), acc, 0, 0, 0);
#pragma unroll
            for (int q = 0; q < 4; ++q) {
                const int row = node0 + hi * 4 + q;
                if (row < nrows) {
                    const int col = t * 16 + ln;
                    float y = acc[q] + b3r[t];
                    if constexpr (SEL) {
                        if (!ivr[q]) y = Xf[(size_t)row * H + col];   // exact f32 passthrough
                    }
                    if constexpr (OUTB) OUTb[(size_t)row * H + col] = bfbits(y);
                    else                OUTf[(size_t)row * H + col] = y;
                }
            }
        }
    }
}

// ---------------- CSR build (counting sort by dst) ---------------------------
__global__ __launch_bounds__(256) void hist_k(const int* __restrict__ dst,
                                              int* __restrict__ cnt, int E) {
    int e = blockIdx.x * 256 + threadIdx.x;
    if (e < E) atomicAdd(&cnt[dst[e]], 1);
}

__global__ __launch_bounds__(256) void scan1_k(const int* __restrict__ cnt,
                                               int* __restrict__ bsum, int N) {
    __shared__ int s[256];
    const int b = blockIdx.x, tid = threadIdx.x;
    const int base = b * CHUNK + tid * 8;
    int sum = 0;
#pragma unroll
    for (int j = 0; j < 8; ++j) { int i = base + j; if (i < N) sum += cnt[i]; }
    s[tid] = sum;
    __syncthreads();
    for (int st = 128; st > 0; st >>= 1) {
        if (tid < st) s[tid] += s[tid + st];
        __syncthreads();
    }
    if (tid == 0) bsum[b] = s[0];
}

__global__ void scan2_k(int* bsum, int nchunks) {
    if (threadIdx.x == 0 && blockIdx.x == 0) {
        int run = 0;
        for (int i = 0; i < nchunks; ++i) { int v = bsum[i]; bsum[i] = run; run += v; }
    }
}

__global__ __launch_bounds__(256) void scan3_k(const int* __restrict__ cnt,
                                               const int* __restrict__ bsum,
                                               int* __restrict__ offsets,
                                               int* __restrict__ cursor, int N) {
    __shared__ int s[256];
    const int b = blockIdx.x, tid = threadIdx.x;
    const int base = b * CHUNK + tid * 8;
    int v[8];
    int tsum = 0;
#pragma unroll
    for (int j = 0; j < 8; ++j) {
        int t = (base + j < N) ? cnt[base + j] : 0;
        v[j] = tsum;                 // exclusive within thread
        tsum += t;
    }
    s[tid] = tsum;
    __syncthreads();
    for (int st = 1; st < 256; st <<= 1) {     // inclusive Hillis-Steele
        int val = (tid >= st) ? s[tid - st] : 0;
        __syncthreads();
        s[tid] += val;
        __syncthreads();
    }
    const int texcl = s[tid] - tsum + bsum[b];
#pragma unroll
    for (int j = 0; j < 8; ++j) {
        int i = base + j;
        if (i < N) { int o = texcl + v[j]; offsets[i] = o; cursor[i] = o; }
    }
}

__global__ __launch_bounds__(256) void scatter_k(const int* __restrict__ src,
                                                 const int* __restrict__ dst,
                                                 const int* __restrict__ r,
                                                 int* __restrict__ cursor,
                                                 int* __restrict__ packed, int E) {
    int e = blockIdx.x * 256 + threadIdx.x;
    if (e >= E) return;
    int d = dst[e];
    int pos = atomicAdd(&cursor[d], 1);
    packed[pos] = src[e] | (r[e] << 31);
}

// one wave per node: 64 lanes x u32(2 bf16) = 128 cols; sum bucket rows (f32
// accum), fold mean, write bf16
__global__ __launch_bounds__(256) void gather_mean_k(
    const ushort_t* __restrict__ featb, const ushort_t* __restrict__ invb,
    const int* __restrict__ offsets, const int* __restrict__ cnt,
    const int* __restrict__ packed, ushort_t* __restrict__ neighb, int N)
{
    const int wv = threadIdx.x >> 6, lane = threadIdx.x & 63;
    const int n = blockIdx.x * 4 + wv;
    if (n >= N) return;
    const int start = offsets[n];
    const int d = cnt[n];
    float a0 = 0.f, a1 = 0.f;
    int k = 0;
    for (; k + 1 < d; k += 2) {                 // 2-way MLP
        const int p0 = packed[start + k];
        const int p1 = packed[start + k + 1];
        const ushort_t* t0 = (p0 < 0) ? invb : featb;
        const ushort_t* t1 = (p1 < 0) ? invb : featb;
        unsigned u0 = *(const unsigned*)(t0 + (size_t)(p0 & 0x7fffffff) * H + lane * 2);
        unsigned u1 = *(const unsigned*)(t1 + (size_t)(p1 & 0x7fffffff) * H + lane * 2);
        a0 += __builtin_bit_cast(float, u0 << 16) + __builtin_bit_cast(float, u1 << 16);
        a1 += __builtin_bit_cast(float, u0 & 0xffff0000u) + __builtin_bit_cast(float, u1 & 0xffff0000u);
    }
    if (k < d) {
        const int p0 = packed[start + k];
        const ushort_t* t0 = (p0 < 0) ? invb : featb;
        unsigned u0 = *(const unsigned*)(t0 + (size_t)(p0 & 0x7fffffff) * H + lane * 2);
        a0 += __builtin_bit_cast(float, u0 << 16);
        a1 += __builtin_bit_cast(float, u0 & 0xffff0000u);
    }
    const float scl = 1.0f / (float)max(d, 1);
    unsigned out = (unsigned)bfbits(a0 * scl) | ((unsigned)bfbits(a1 * scl) << 16);
    *(unsigned*)(neighb + (size_t)n * H + lane * 2) = out;
}

extern "C" void kernel_launch(void* const* d_in, const int* in_sizes, int n_in,
                              void* d_out, int out_size, void* d_ws, size_t ws_size,
                              hipStream_t stream) {
    const float* feat = (const float*)d_in[0];
    const int*   src  = (const int*)d_in[1];
    const int*   dst  = (const int*)d_in[2];
    const int*   r    = (const int*)d_in[3];
    const int*   inv  = (const int*)d_in[4];
    const float* iw1 = (const float*)d_in[5],  *ib1 = (const float*)d_in[6];
    const float* iw2 = (const float*)d_in[7],  *ib2 = (const float*)d_in[8];
    const float* iw3 = (const float*)d_in[9],  *ib3 = (const float*)d_in[10];
    const float* aw1 = (const float*)d_in[11], *ab1 = (const float*)d_in[12];
    const float* aw2 = (const float*)d_in[13], *ab2 = (const float*)d_in[14];
    const float* aw3 = (const float*)d_in[15], *ab3 = (const float*)d_in[16];

    const int N = in_sizes[4];   // inv is [N]
    const int E = in_sizes[1];   // src is [E]

    // region A: phase-1 bf16 tables, aliased later by f32 res
    ushort_t* featb = (ushort_t*)d_ws;              // N*H bf16
    ushort_t* invb  = featb + (size_t)N * H;        // N*H bf16
    float*    res   = (float*)d_ws;                 // N*H f32 (aliases featb+invb)
    // region B
    ushort_t* neighb = invb + (size_t)N * H;        // N*H bf16
    // ints
    int* cnt     = (int*)(neighb + (size_t)N * H);
    int* offsets = cnt + N;
    int* cursor  = offsets + N;
    int* packed  = cursor + N;
    int* bsum    = packed + E;

    const int nchunks = (N + CHUNK - 1) / CHUNK;
    const int ntiles  = (N + 15) / 16;
    const int eblk    = (E + 255) / 256;
    const int pblk    = min((ntiles + 3) / 4, 768);   // 3 blocks/CU x 256 CUs

    hipMemsetAsync(cnt, 0, (size_t)N * sizeof(int), stream);

    // 1) invb = bf16(mlp_inv(feat)); featb = bf16(feat)
    mlp3_t<false, true, true, false><<<pblk, 256, 0, stream>>>(
        feat, iw1, ib1, iw2, ib2, iw3, ib3, invb, featb, nullptr, N, ntiles);
    // 2) CSR build
    hist_k<<<eblk, 256, 0, stream>>>(dst, cnt, E);
    scan1_k<<<nchunks, 256, 0, stream>>>(cnt, bsum, N);
    scan2_k<<<1, 64, 0, stream>>>(bsum, nchunks);
    scan3_k<<<nchunks, 256, 0, stream>>>(cnt, bsum, offsets, cursor, N);
    scatter_k<<<eblk, 256, 0, stream>>>(src, dst, r, cursor, packed, E);
    // 3) neighb = bf16(mean of messages)
    gather_mean_k<<<(N + 3) / 4, 256, 0, stream>>>(featb, invb, offsets, cnt,
                                                   packed, neighb, N);
    // 4) res = mlp_and(neighb)   (f32, overwrites featb/invb region)
    mlp3_t<true, false, false, false><<<pblk, 256, 0, stream>>>(
        neighb, aw1, ab1, aw2, ab2, aw3, ab3, res, nullptr, nullptr, N, ntiles);
    // 5) out = inv ? mlp_inv(res) : res
    mlp3_t<false, false, false, true><<<pblk, 256, 0, stream>>>(
        res, iw1, ib1, iw2, ib2, iw3, ib3, d_out, nullptr, inv, N, ntiles);
}

// Round 4
// 220.285 us; speedup vs baseline: 6.9957x; 1.1809x over previous
//
#include <hip/hip_runtime.h>

// FuncConv: out = select(inv, mlp_inv(res), res); res = mlp_and(mean_dst(msg));
// msg = select(r, mlp_inv(feat[src]), feat[src]).
// R3: (a) MLP blocks 512-thr / 56KB LDS -> 16 waves/CU (was 12), staged
//     coalesced bf16 stores; (b) pass-4 writes d_out directly, pass-5 runs
//     only on inv==1 rows via ordered ilist built in the scan (no res buffer);
// (c) gather: paired-row 8B loads + 2x unroll + shfl_xor combine;
// (d) scan2 single-wave shuffle scan (was serial thread-0 loop).
//
// ws: featb[N*H bf16] invb[N*H bf16] neighb[N*H bf16]
//     cnt[N] offsets[N] cursor[N] ilist[N] packed[E] bsum[256] bsumI[256] icnt

#define H 128
#define HH 64
#define CHUNK 2048
#define NW 8   // waves per MLP block

typedef float f32x4 __attribute__((ext_vector_type(4)));
typedef __bf16 bf16x8 __attribute__((ext_vector_type(8)));
typedef unsigned short us8 __attribute__((ext_vector_type(8)));
typedef unsigned short ushort_t;

__device__ __forceinline__ unsigned short bfbits(float f) {
    __bf16 h = (__bf16)f;                       // RNE convert
    return __builtin_bit_cast(unsigned short, h);
}
__device__ __forceinline__ bf16x8 as_bf16x8(us8 v) {
    return __builtin_bit_cast(bf16x8, v);
}
__device__ __forceinline__ float blo(unsigned u) {
    return __builtin_bit_cast(float, u << 16);
}
__device__ __forceinline__ float bhi(unsigned u) {
    return __builtin_bit_cast(float, u & 0xffff0000u);
}

// per-wave transpose buffer: 16 rows x 64 cols bf16, XOR-swizzled
__device__ __forceinline__ int tb_off(int m, int j) {
    return m * 64 + ((((j * 2) ^ ((m & 7) << 4))) >> 1);
}
__device__ __forceinline__ bf16x8 ld_tb(const unsigned short* tb, int m, int j0) {
    return as_bf16x8(*(const us8*)&tb[tb_off(m, j0)]);
}
__device__ __forceinline__ bf16x8 ld_fr(const unsigned short* FR, int fid, int lane) {
    return as_bf16x8(*(const us8*)&FR[(fid * 64 + lane) * 8]);
}

// ---------------- fused 3-layer MLP, persistent blocks -----------------------
// INB:  X is bf16 row-major, else f32
// OUTB: OUT is bf16 (stores staged through LDS, coalesced), else f32 direct
// WF:   also write bf16 copy of X to featb (requires !INB)
// LIST: rows come from rows[] (count in rowcnt[0]); out rows likewise
template<bool INB, bool OUTB, bool WF, bool LIST>
__global__ __launch_bounds__(512, 4) void mlp3_t(
    const void* X_,
    const float* __restrict__ W1, const float* __restrict__ B1,
    const float* __restrict__ W2, const float* __restrict__ B2,
    const float* __restrict__ W3, const float* __restrict__ B3,
    void* OUT_,
    ushort_t* __restrict__ featb,
    const int* __restrict__ rows, const int* __restrict__ rowcnt,
    int nrows, int ntiles)
{
    __shared__ __align__(16) unsigned short FR[40 * 64 * 8];    // 40 KB
    __shared__ __align__(16) unsigned short TBs[NW * 16 * 64];  // 16 KB
    const float*    Xf = (const float*)X_;
    const ushort_t* Xb = (const ushort_t*)X_;

    const int tid  = threadIdx.x;
    const int wv   = tid >> 6;
    const int lane = tid & 63;
    const int ln   = lane & 15;
    const int hi   = lane >> 4;

    // stage all weight B-fragments once per block
    for (int fid = wv; fid < 40; fid += NW) {
        const float* w; int inF, s, t;
        if (fid < 16)      { w = W1; inF = H;  s = fid >> 2;        t = fid & 3; }
        else if (fid < 24) { w = W2; inF = HH; s = (fid - 16) >> 2; t = (fid - 16) & 3; }
        else               { w = W3; inF = HH; s = (fid - 24) >> 3; t = (fid - 24) & 7; }
        const float* p = w + (size_t)(t * 16 + ln) * inF + (s * 32 + hi * 8);
        f32x4 a = *(const f32x4*)p;
        f32x4 b = *(const f32x4*)(p + 4);
        unsigned short* d = &FR[(fid * 64 + lane) * 8];
        d[0] = bfbits(a[0]); d[1] = bfbits(a[1]); d[2] = bfbits(a[2]); d[3] = bfbits(a[3]);
        d[4] = bfbits(b[0]); d[5] = bfbits(b[1]); d[6] = bfbits(b[2]); d[7] = bfbits(b[3]);
    }
    float b1r[4], b2r[4], b3r[8];
#pragma unroll
    for (int t = 0; t < 4; ++t) b1r[t] = B1[t * 16 + ln];
#pragma unroll
    for (int t = 0; t < 4; ++t) b2r[t] = B2[t * 16 + ln];
#pragma unroll
    for (int t = 0; t < 8; ++t) b3r[t] = B3[t * 16 + ln];
    __syncthreads();

    int rcnt, tcount;
    if constexpr (LIST) { rcnt = rowcnt[0]; tcount = (rcnt + 15) >> 4; }
    else                { rcnt = nrows;     tcount = ntiles; }

    unsigned short* tb = &TBs[wv * 16 * 64];

    for (int tile = blockIdx.x * NW + wv; tile < tcount; tile += gridDim.x * NW) {
        const int node0 = tile * 16;
        const int lpos  = min(node0 + ln, rcnt - 1);
        const int arow  = LIST ? rows[lpos] : lpos;
        const size_t ro = (size_t)arow * H;

        bf16x8 a1[4];
#pragma unroll
        for (int s = 0; s < 4; ++s) {
            if constexpr (INB) {
                a1[s] = as_bf16x8(*(const us8*)(Xb + ro + s * 32 + hi * 8));
            } else {
                f32x4 u = *(const f32x4*)(Xf + ro + s * 32 + hi * 8);
                f32x4 v = *(const f32x4*)(Xf + ro + s * 32 + hi * 8 + 4);
                bf16x8 f;
                f[0] = (__bf16)u[0]; f[1] = (__bf16)u[1]; f[2] = (__bf16)u[2]; f[3] = (__bf16)u[3];
                f[4] = (__bf16)v[0]; f[5] = (__bf16)v[1]; f[6] = (__bf16)v[2]; f[7] = (__bf16)v[3];
                a1[s] = f;
                if constexpr (WF)
                    *(us8*)(featb + ro + s * 32 + hi * 8) = __builtin_bit_cast(us8, f);
            }
        }

        // layer 1
#pragma unroll
        for (int t = 0; t < 4; ++t) {
            f32x4 acc = {0.f, 0.f, 0.f, 0.f};
#pragma unroll
            for (int s = 0; s < 4; ++s)
                acc = __builtin_amdgcn_mfma_f32_16x16x32_bf16(a1[s], ld_fr(FR, s * 4 + t, lane), acc, 0, 0, 0);
#pragma unroll
            for (int q = 0; q < 4; ++q) {
                float y = acc[q] + b1r[t];
                y = (y >= 0.f) ? y : 0.01f * y;
                tb[tb_off(hi * 4 + q, t * 16 + ln)] = bfbits(y);
            }
        }

        // layer 2
        bf16x8 a2[2];
#pragma unroll
        for (int s = 0; s < 2; ++s) a2[s] = ld_tb(tb, ln, s * 32 + hi * 8);
#pragma unroll
        for (int t = 0; t < 4; ++t) {
            f32x4 acc = {0.f, 0.f, 0.f, 0.f};
#pragma unroll
            for (int s = 0; s < 2; ++s)
                acc = __builtin_amdgcn_mfma_f32_16x16x32_bf16(a2[s], ld_fr(FR, 16 + s * 4 + t, lane), acc, 0, 0, 0);
#pragma unroll
            for (int q = 0; q < 4; ++q) {
                float y = acc[q] + b2r[t];
                y = (y >= 0.f) ? y : 0.01f * y;
                tb[tb_off(hi * 4 + q, t * 16 + ln)] = bfbits(y);
            }
        }

        // layer 3
        bf16x8 a3[2];
#pragma unroll
        for (int s = 0; s < 2; ++s) a3[s] = ld_tb(tb, ln, s * 32 + hi * 8);

        if constexpr (OUTB) {
            ushort_t* OUTb = (ushort_t*)OUT_;
#pragma unroll
            for (int half = 0; half < 2; ++half) {
#pragma unroll
                for (int t2 = 0; t2 < 4; ++t2) {
                    const int t = half * 4 + t2;
                    f32x4 acc = {0.f, 0.f, 0.f, 0.f};
#pragma unroll
                    for (int s = 0; s < 2; ++s)
                        acc = __builtin_amdgcn_mfma_f32_16x16x32_bf16(a3[s], ld_fr(FR, 24 + s * 8 + t, lane), acc, 0, 0, 0);
#pragma unroll
                    for (int q = 0; q < 4; ++q)
                        tb[tb_off(hi * 4 + q, t2 * 16 + ln)] = bfbits(acc[q] + b3r[t]);
                }
                const int rr = lane >> 2, c0 = (lane & 3) * 16;
                if (node0 + rr < rcnt) {
                    us8 w0 = __builtin_bit_cast(us8, ld_tb(tb, rr, c0));
                    us8 w1 = __builtin_bit_cast(us8, ld_tb(tb, rr, c0 + 8));
                    ushort_t* op = OUTb + (size_t)(node0 + rr) * H + half * 64 + c0;
                    *(us8*)op = w0;
                    *(us8*)(op + 8) = w1;
                }
            }
        } else {
            float* OUTf = (float*)OUT_;
            int grow[4];
#pragma unroll
            for (int q = 0; q < 4; ++q) {
                const int pos = node0 + hi * 4 + q;
                grow[q] = (pos < rcnt) ? (LIST ? rows[pos] : pos) : -1;
            }
#pragma unroll
            for (int t = 0; t < 8; ++t) {
                f32x4 acc = {0.f, 0.f, 0.f, 0.f};
#pragma unroll
                for (int s = 0; s < 2; ++s)
                    acc = __builtin_amdgcn_mfma_f32_16x16x32_bf16(a3[s], ld_fr(FR, 24 + s * 8 + t, lane), acc, 0, 0, 0);
#pragma unroll
                for (int q = 0; q < 4; ++q) {
                    if (grow[q] >= 0)
                        OUTf[(size_t)grow[q] * H + t * 16 + ln] = acc[q] + b3r[t];
                }
            }
        }
    }
}

// ---------------- CSR build (counting sort by dst) ---------------------------
__global__ __launch_bounds__(256) void hist_k(const int* __restrict__ dst,
                                              int* __restrict__ cnt, int E) {
    int e = blockIdx.x * 256 + threadIdx.x;
    if (e < E) atomicAdd(&cnt[dst[e]], 1);
}

__global__ __launch_bounds__(256) void scan1_k(const int* __restrict__ cnt,
                                               const int* __restrict__ inv,
                                               int* __restrict__ bsum,
                                               int* __restrict__ bsumI, int N) {
    __shared__ int s[256], si[256];
    const int b = blockIdx.x, tid = threadIdx.x;
    const int base = b * CHUNK + tid * 8;
    int sum = 0, sumi = 0;
#pragma unroll
    for (int j = 0; j < 8; ++j) {
        int i = base + j;
        if (i < N) { sum += cnt[i]; sumi += inv[i]; }
    }
    s[tid] = sum; si[tid] = sumi;
    __syncthreads();
    for (int st = 128; st > 0; st >>= 1) {
        if (tid < st) { s[tid] += s[tid + st]; si[tid] += si[tid + st]; }
        __syncthreads();
    }
    if (tid == 0) { bsum[b] = s[0]; bsumI[b] = si[0]; }
}

__global__ void scan2_k(int* bsum, int* bsumI, int* icnt, int nchunks) {
    const int lane = threadIdx.x;
    if (nchunks <= 64) {
        int v = (lane < nchunks) ? bsum[lane] : 0;
        int o = v;
        for (int st = 1; st < 64; st <<= 1) { int w = __shfl_up(v, st); if (lane >= st) v += w; }
        if (lane < nchunks) bsum[lane] = v - o;
        int u = (lane < nchunks) ? bsumI[lane] : 0;
        int ou = u;
        for (int st = 1; st < 64; st <<= 1) { int w = __shfl_up(u, st); if (lane >= st) u += w; }
        if (lane < nchunks) bsumI[lane] = u - ou;
        if (lane == 63) icnt[0] = u;
    } else if (lane == 0) {
        int run = 0, runi = 0;
        for (int i = 0; i < nchunks; ++i) {
            int v = bsum[i];  bsum[i]  = run;  run  += v;
            int u = bsumI[i]; bsumI[i] = runi; runi += u;
        }
        icnt[0] = runi;
    }
}

__global__ __launch_bounds__(256) void scan3_k(const int* __restrict__ cnt,
                                               const int* __restrict__ inv,
                                               const int* __restrict__ bsum,
                                               const int* __restrict__ bsumI,
                                               int* __restrict__ offsets,
                                               int* __restrict__ cursor,
                                               int* __restrict__ ilist, int N) {
    __shared__ int s[256];
    const int b = blockIdx.x, tid = threadIdx.x;
    const int base = b * CHUNK + tid * 8;

    // phase A: cnt -> offsets/cursor
    int v[8]; int tsum = 0;
#pragma unroll
    for (int j = 0; j < 8; ++j) {
        int t = (base + j < N) ? cnt[base + j] : 0;
        v[j] = tsum; tsum += t;
    }
    s[tid] = tsum;
    __syncthreads();
    for (int st = 1; st < 256; st <<= 1) {
        int val = (tid >= st) ? s[tid - st] : 0;
        __syncthreads();
        s[tid] += val;
        __syncthreads();
    }
    const int texcl = s[tid] - tsum + bsum[b];
#pragma unroll
    for (int j = 0; j < 8; ++j) {
        int i = base + j;
        if (i < N) { int o = texcl + v[j]; offsets[i] = o; cursor[i] = o; }
    }
    __syncthreads();

    // phase B: inv -> ordered ilist
    int vi[8]; int tsumi = 0;
#pragma unroll
    for (int j = 0; j < 8; ++j) {
        int t = (base + j < N) ? inv[base + j] : 0;
        vi[j] = tsumi; tsumi += t;
    }
    s[tid] = tsumi;
    __syncthreads();
    for (int st = 1; st < 256; st <<= 1) {
        int val = (tid >= st) ? s[tid - st] : 0;
        __syncthreads();
        s[tid] += val;
        __syncthreads();
    }
    const int texclI = s[tid] - tsumi + bsumI[b];
#pragma unroll
    for (int j = 0; j < 8; ++j) {
        int i = base + j;
        if (i < N && inv[i]) ilist[texclI + vi[j]] = i;
    }
}

__global__ __launch_bounds__(256) void scatter_k(const int* __restrict__ src,
                                                 const int* __restrict__ dst,
                                                 const int* __restrict__ r,
                                                 int* __restrict__ cursor,
                                                 int* __restrict__ packed, int E) {
    int e = blockIdx.x * 256 + threadIdx.x;
    if (e >= E) return;
    int d = dst[e];
    int pos = atomicAdd(&cursor[d], 1);
    packed[pos] = src[e] | (r[e] << 31);
}

// one wave per node: 2 rows x 32 lanes x 8B per load; f32 accum; shfl combine
__global__ __launch_bounds__(256) void gather_mean_k(
    const ushort_t* __restrict__ featb, const ushort_t* __restrict__ invb,
    const int* __restrict__ offsets, const int* __restrict__ cnt,
    const int* __restrict__ packed, ushort_t* __restrict__ neighb, int N)
{
    const int wv = threadIdx.x >> 6, lane = threadIdx.x & 63;
    const int n = blockIdx.x * 4 + wv;
    if (n >= N) return;
    const int start = offsets[n];
    const int d = cnt[n];
    const int half = lane >> 5;
    const size_t co = (size_t)(lane & 31) * 4;
    float a0 = 0.f, a1 = 0.f, a2 = 0.f, a3 = 0.f;
    int k = 0;
    for (; k + 3 < d; k += 4) {
        const int pA = packed[start + k + half];
        const int pB = packed[start + k + 2 + half];
        const ushort_t* tA = (pA < 0) ? invb : featb;
        const ushort_t* tB = (pB < 0) ? invb : featb;
        const uint2 uA = *(const uint2*)(tA + (size_t)(pA & 0x7fffffff) * H + co);
        const uint2 uB = *(const uint2*)(tB + (size_t)(pB & 0x7fffffff) * H + co);
        a0 += blo(uA.x) + blo(uB.x);
        a1 += bhi(uA.x) + bhi(uB.x);
        a2 += blo(uA.y) + blo(uB.y);
        a3 += bhi(uA.y) + bhi(uB.y);
    }
    if (k + 1 < d) {
        const int p = packed[start + k + half];
        const ushort_t* t = (p < 0) ? invb : featb;
        const uint2 u = *(const uint2*)(t + (size_t)(p & 0x7fffffff) * H + co);
        a0 += blo(u.x); a1 += bhi(u.x); a2 += blo(u.y); a3 += bhi(u.y);
        k += 2;
    }
    if (k < d && half == 0) {
        const int p = packed[start + k];
        const ushort_t* t = (p < 0) ? invb : featb;
        const uint2 u = *(const uint2*)(t + (size_t)(p & 0x7fffffff) * H + co);
        a0 += blo(u.x); a1 += bhi(u.x); a2 += blo(u.y); a3 += bhi(u.y);
    }
    a0 += __shfl_xor(a0, 32);
    a1 += __shfl_xor(a1, 32);
    a2 += __shfl_xor(a2, 32);
    a3 += __shfl_xor(a3, 32);
    if (half == 0) {
        const float scl = 1.0f / (float)max(d, 1);
        uint2 o;
        o.x = (unsigned)bfbits(a0 * scl) | ((unsigned)bfbits(a1 * scl) << 16);
        o.y = (unsigned)bfbits(a2 * scl) | ((unsigned)bfbits(a3 * scl) << 16);
        *(uint2*)(neighb + (size_t)n * H + co) = o;
    }
}

extern "C" void kernel_launch(void* const* d_in, const int* in_sizes, int n_in,
                              void* d_out, int out_size, void* d_ws, size_t ws_size,
                              hipStream_t stream) {
    const float* feat = (const float*)d_in[0];
    const int*   src  = (const int*)d_in[1];
    const int*   dst  = (const int*)d_in[2];
    const int*   r    = (const int*)d_in[3];
    const int*   inv  = (const int*)d_in[4];
    const float* iw1 = (const float*)d_in[5],  *ib1 = (const float*)d_in[6];
    const float* iw2 = (const float*)d_in[7],  *ib2 = (const float*)d_in[8];
    const float* iw3 = (const float*)d_in[9],  *ib3 = (const float*)d_in[10];
    const float* aw1 = (const float*)d_in[11], *ab1 = (const float*)d_in[12];
    const float* aw2 = (const float*)d_in[13], *ab2 = (const float*)d_in[14];
    const float* aw3 = (const float*)d_in[15], *ab3 = (const float*)d_in[16];

    const int N = in_sizes[4];   // inv is [N]
    const int E = in_sizes[1];   // src is [E]

    ushort_t* featb  = (ushort_t*)d_ws;             // N*H bf16
    ushort_t* invb   = featb + (size_t)N * H;       // N*H bf16
    ushort_t* neighb = invb + (size_t)N * H;        // N*H bf16
    int* cnt     = (int*)(neighb + (size_t)N * H);
    int* offsets = cnt + N;
    int* cursor  = offsets + N;
    int* ilist   = cursor + N;
    int* packed  = ilist + N;
    int* bsum    = packed + E;
    int* bsumI   = bsum + 256;
    int* icnt    = bsumI + 256;

    const int nchunks = (N + CHUNK - 1) / CHUNK;
    const int ntiles  = (N + 15) / 16;
    const int eblk    = (E + 255) / 256;
    const int g1      = min((ntiles + NW - 1) / NW, 512);  // 2 blocks/CU

    hipMemsetAsync(cnt, 0, (size_t)N * sizeof(int), stream);

    // 1) invb = bf16(mlp_inv(feat)); featb = bf16(feat)
    mlp3_t<false, true, true, false><<<g1, 512, 0, stream>>>(
        feat, iw1, ib1, iw2, ib2, iw3, ib3, invb, featb, nullptr, nullptr, N, ntiles);
    // 2) CSR build (+ ordered inv-list)
    hist_k<<<eblk, 256, 0, stream>>>(dst, cnt, E);
    scan1_k<<<nchunks, 256, 0, stream>>>(cnt, inv, bsum, bsumI, N);
    scan2_k<<<1, 64, 0, stream>>>(bsum, bsumI, icnt, nchunks);
    scan3_k<<<nchunks, 256, 0, stream>>>(cnt, inv, bsum, bsumI, offsets, cursor, ilist, N);
    scatter_k<<<eblk, 256, 0, stream>>>(src, dst, r, cursor, packed, E);
    // 3) neighb = bf16(mean of messages)
    gather_mean_k<<<(N + 3) / 4, 256, 0, stream>>>(featb, invb, offsets, cnt,
                                                   packed, neighb, N);
    // 4) d_out = mlp_and(neighb)  (f32, all rows)
    mlp3_t<true, false, false, false><<<g1, 512, 0, stream>>>(
        neighb, aw1, ab1, aw2, ab2, aw3, ab3, d_out, nullptr, nullptr, nullptr, N, ntiles);
    // 5) d_out[ilist] = mlp_inv(d_out[ilist])  (sparse, ~50% of rows)
    mlp3_t<false, false, false, true><<<256, 512, 0, stream>>>(
        d_out, iw1, ib1, iw2, ib2, iw3, ib3, d_out, nullptr, ilist, icnt, N, ntiles);
}

// Round 5
// 193.473 us; speedup vs baseline: 7.9652x; 1.1386x over previous
//
#include <hip/hip_runtime.h>

// FuncConv: out = select(inv, mlp_inv(res), res); res = mlp_and(mean_dst(msg));
// msg = select(r, mlp_inv(feat[src]), feat[src]).
// R4: (a) scatter_k (59us, WRITE 55MB = 17x amplification from cross-XCD 4B
//     scatter) -> two-level counting sort: coarse_bin (LDS hist, block-run
//     contiguous writes) + fine_scatter (one block per 512-node bucket, LDS
//     cursors, 16KB output region stays in one XCD L2);
// (b) gather: 16B/lane loads, 8 rows in flight, shfl_xor(16/32) combine.
//
// ws: featb[N*H bf16] invb[N*H bf16] neighb[N*H bf16]
//     cnt[N] offsets[N] ilist[N] ebuf[E] packed[E] bsum[256] bsumI[256]
//     icnt[1] ccur[256]

#define H 128
#define HH 64
#define CHUNK 2048
#define NW 8      // waves per MLP block
#define BSH 9     // log2 nodes per coarse bucket
#define BSZ 512   // nodes per coarse bucket
#define ACH 2048  // edges per coarse_bin block

typedef float f32x4 __attribute__((ext_vector_type(4)));
typedef __bf16 bf16x8 __attribute__((ext_vector_type(8)));
typedef unsigned short us8 __attribute__((ext_vector_type(8)));
typedef unsigned short ushort_t;

__device__ __forceinline__ unsigned short bfbits(float f) {
    __bf16 h = (__bf16)f;                       // RNE convert
    return __builtin_bit_cast(unsigned short, h);
}
__device__ __forceinline__ bf16x8 as_bf16x8(us8 v) {
    return __builtin_bit_cast(bf16x8, v);
}
__device__ __forceinline__ float bfl(unsigned short u) {
    return __builtin_bit_cast(float, ((unsigned)u) << 16);
}

// per-wave transpose buffer: 16 rows x 64 cols bf16, XOR-swizzled
__device__ __forceinline__ int tb_off(int m, int j) {
    return m * 64 + ((((j * 2) ^ ((m & 7) << 4))) >> 1);
}
__device__ __forceinline__ bf16x8 ld_tb(const unsigned short* tb, int m, int j0) {
    return as_bf16x8(*(const us8*)&tb[tb_off(m, j0)]);
}
__device__ __forceinline__ bf16x8 ld_fr(const unsigned short* FR, int fid, int lane) {
    return as_bf16x8(*(const us8*)&FR[(fid * 64 + lane) * 8]);
}

// ---------------- fused 3-layer MLP, persistent blocks (unchanged, R3) -------
// INB:  X is bf16 row-major, else f32
// OUTB: OUT is bf16 (stores staged through LDS, coalesced), else f32 direct
// WF:   also write bf16 copy of X to featb (requires !INB)
// LIST: rows come from rows[] (count in rowcnt[0]); out rows likewise
template<bool INB, bool OUTB, bool WF, bool LIST>
__global__ __launch_bounds__(512, 4) void mlp3_t(
    const void* X_,
    const float* __restrict__ W1, const float* __restrict__ B1,
    const float* __restrict__ W2, const float* __restrict__ B2,
    const float* __restrict__ W3, const float* __restrict__ B3,
    void* OUT_,
    ushort_t* __restrict__ featb,
    const int* __restrict__ rows, const int* __restrict__ rowcnt,
    int nrows, int ntiles)
{
    __shared__ __align__(16) unsigned short FR[40 * 64 * 8];    // 40 KB
    __shared__ __align__(16) unsigned short TBs[NW * 16 * 64];  // 16 KB
    const float*    Xf = (const float*)X_;
    const ushort_t* Xb = (const ushort_t*)X_;

    const int tid  = threadIdx.x;
    const int wv   = tid >> 6;
    const int lane = tid & 63;
    const int ln   = lane & 15;
    const int hi   = lane >> 4;

    for (int fid = wv; fid < 40; fid += NW) {
        const float* w; int inF, s, t;
        if (fid < 16)      { w = W1; inF = H;  s = fid >> 2;        t = fid & 3; }
        else if (fid < 24) { w = W2; inF = HH; s = (fid - 16) >> 2; t = (fid - 16) & 3; }
        else               { w = W3; inF = HH; s = (fid - 24) >> 3; t = (fid - 24) & 7; }
        const float* p = w + (size_t)(t * 16 + ln) * inF + (s * 32 + hi * 8);
        f32x4 a = *(const f32x4*)p;
        f32x4 b = *(const f32x4*)(p + 4);
        unsigned short* d = &FR[(fid * 64 + lane) * 8];
        d[0] = bfbits(a[0]); d[1] = bfbits(a[1]); d[2] = bfbits(a[2]); d[3] = bfbits(a[3]);
        d[4] = bfbits(b[0]); d[5] = bfbits(b[1]); d[6] = bfbits(b[2]); d[7] = bfbits(b[3]);
    }
    float b1r[4], b2r[4], b3r[8];
#pragma unroll
    for (int t = 0; t < 4; ++t) b1r[t] = B1[t * 16 + ln];
#pragma unroll
    for (int t = 0; t < 4; ++t) b2r[t] = B2[t * 16 + ln];
#pragma unroll
    for (int t = 0; t < 8; ++t) b3r[t] = B3[t * 16 + ln];
    __syncthreads();

    int rcnt, tcount;
    if constexpr (LIST) { rcnt = rowcnt[0]; tcount = (rcnt + 15) >> 4; }
    else                { rcnt = nrows;     tcount = ntiles; }

    unsigned short* tb = &TBs[wv * 16 * 64];

    for (int tile = blockIdx.x * NW + wv; tile < tcount; tile += gridDim.x * NW) {
        const int node0 = tile * 16;
        const int lpos  = min(node0 + ln, rcnt - 1);
        const int arow  = LIST ? rows[lpos] : lpos;
        const size_t ro = (size_t)arow * H;

        bf16x8 a1[4];
#pragma unroll
        for (int s = 0; s < 4; ++s) {
            if constexpr (INB) {
                a1[s] = as_bf16x8(*(const us8*)(Xb + ro + s * 32 + hi * 8));
            } else {
                f32x4 u = *(const f32x4*)(Xf + ro + s * 32 + hi * 8);
                f32x4 v = *(const f32x4*)(Xf + ro + s * 32 + hi * 8 + 4);
                bf16x8 f;
                f[0] = (__bf16)u[0]; f[1] = (__bf16)u[1]; f[2] = (__bf16)u[2]; f[3] = (__bf16)u[3];
                f[4] = (__bf16)v[0]; f[5] = (__bf16)v[1]; f[6] = (__bf16)v[2]; f[7] = (__bf16)v[3];
                a1[s] = f;
                if constexpr (WF)
                    *(us8*)(featb + ro + s * 32 + hi * 8) = __builtin_bit_cast(us8, f);
            }
        }

        // layer 1
#pragma unroll
        for (int t = 0; t < 4; ++t) {
            f32x4 acc = {0.f, 0.f, 0.f, 0.f};
#pragma unroll
            for (int s = 0; s < 4; ++s)
                acc = __builtin_amdgcn_mfma_f32_16x16x32_bf16(a1[s], ld_fr(FR, s * 4 + t, lane), acc, 0, 0, 0);
#pragma unroll
            for (int q = 0; q < 4; ++q) {
                float y = acc[q] + b1r[t];
                y = (y >= 0.f) ? y : 0.01f * y;
                tb[tb_off(hi * 4 + q, t * 16 + ln)] = bfbits(y);
            }
        }

        // layer 2
        bf16x8 a2[2];
#pragma unroll
        for (int s = 0; s < 2; ++s) a2[s] = ld_tb(tb, ln, s * 32 + hi * 8);
#pragma unroll
        for (int t = 0; t < 4; ++t) {
            f32x4 acc = {0.f, 0.f, 0.f, 0.f};
#pragma unroll
            for (int s = 0; s < 2; ++s)
                acc = __builtin_amdgcn_mfma_f32_16x16x32_bf16(a2[s], ld_fr(FR, 16 + s * 4 + t, lane), acc, 0, 0, 0);
#pragma unroll
            for (int q = 0; q < 4; ++q) {
                float y = acc[q] + b2r[t];
                y = (y >= 0.f) ? y : 0.01f * y;
                tb[tb_off(hi * 4 + q, t * 16 + ln)] = bfbits(y);
            }
        }

        // layer 3
        bf16x8 a3[2];
#pragma unroll
        for (int s = 0; s < 2; ++s) a3[s] = ld_tb(tb, ln, s * 32 + hi * 8);

        if constexpr (OUTB) {
            ushort_t* OUTb = (ushort_t*)OUT_;
#pragma unroll
            for (int half = 0; half < 2; ++half) {
#pragma unroll
                for (int t2 = 0; t2 < 4; ++t2) {
                    const int t = half * 4 + t2;
                    f32x4 acc = {0.f, 0.f, 0.f, 0.f};
#pragma unroll
                    for (int s = 0; s < 2; ++s)
                        acc = __builtin_amdgcn_mfma_f32_16x16x32_bf16(a3[s], ld_fr(FR, 24 + s * 8 + t, lane), acc, 0, 0, 0);
#pragma unroll
                    for (int q = 0; q < 4; ++q)
                        tb[tb_off(hi * 4 + q, t2 * 16 + ln)] = bfbits(acc[q] + b3r[t]);
                }
                const int rr = lane >> 2, c0 = (lane & 3) * 16;
                if (node0 + rr < rcnt) {
                    us8 w0 = __builtin_bit_cast(us8, ld_tb(tb, rr, c0));
                    us8 w1 = __builtin_bit_cast(us8, ld_tb(tb, rr, c0 + 8));
                    ushort_t* op = OUTb + (size_t)(node0 + rr) * H + half * 64 + c0;
                    *(us8*)op = w0;
                    *(us8*)(op + 8) = w1;
                }
            }
        } else {
            float* OUTf = (float*)OUT_;
            int grow[4];
#pragma unroll
            for (int q = 0; q < 4; ++q) {
                const int pos = node0 + hi * 4 + q;
                grow[q] = (pos < rcnt) ? (LIST ? rows[pos] : pos) : -1;
            }
#pragma unroll
            for (int t = 0; t < 8; ++t) {
                f32x4 acc = {0.f, 0.f, 0.f, 0.f};
#pragma unroll
                for (int s = 0; s < 2; ++s)
                    acc = __builtin_amdgcn_mfma_f32_16x16x32_bf16(a3[s], ld_fr(FR, 24 + s * 8 + t, lane), acc, 0, 0, 0);
#pragma unroll
                for (int q = 0; q < 4; ++q) {
                    if (grow[q] >= 0)
                        OUTf[(size_t)grow[q] * H + t * 16 + ln] = acc[q] + b3r[t];
                }
            }
        }
    }
}

// ---------------- CSR build (two-level counting sort by dst) -----------------
__global__ __launch_bounds__(256) void hist_k(const int* __restrict__ dst,
                                              int* __restrict__ cnt, int E) {
    int e = blockIdx.x * 256 + threadIdx.x;
    if (e < E) atomicAdd(&cnt[dst[e]], 1);
}

__global__ __launch_bounds__(256) void scan1_k(const int* __restrict__ cnt,
                                               const int* __restrict__ inv,
                                               int* __restrict__ bsum,
                                               int* __restrict__ bsumI, int N) {
    __shared__ int s[256], si[256];
    const int b = blockIdx.x, tid = threadIdx.x;
    const int base = b * CHUNK + tid * 8;
    int sum = 0, sumi = 0;
#pragma unroll
    for (int j = 0; j < 8; ++j) {
        int i = base + j;
        if (i < N) { sum += cnt[i]; sumi += inv[i]; }
    }
    s[tid] = sum; si[tid] = sumi;
    __syncthreads();
    for (int st = 128; st > 0; st >>= 1) {
        if (tid < st) { s[tid] += s[tid + st]; si[tid] += si[tid + st]; }
        __syncthreads();
    }
    if (tid == 0) { bsum[b] = s[0]; bsumI[b] = si[0]; }
}

__global__ void scan2_k(int* bsum, int* bsumI, int* icnt, int nchunks) {
    const int lane = threadIdx.x;
    if (nchunks <= 64) {
        int v = (lane < nchunks) ? bsum[lane] : 0;
        int o = v;
        for (int st = 1; st < 64; st <<= 1) { int w = __shfl_up(v, st); if (lane >= st) v += w; }
        if (lane < nchunks) bsum[lane] = v - o;
        int u = (lane < nchunks) ? bsumI[lane] : 0;
        int ou = u;
        for (int st = 1; st < 64; st <<= 1) { int w = __shfl_up(u, st); if (lane >= st) u += w; }
        if (lane < nchunks) bsumI[lane] = u - ou;
        if (lane == 63) icnt[0] = u;
    } else if (lane == 0) {
        int run = 0, runi = 0;
        for (int i = 0; i < nchunks; ++i) {
            int v = bsum[i];  bsum[i]  = run;  run  += v;
            int u = bsumI[i]; bsumI[i] = runi; runi += u;
        }
        icnt[0] = runi;
    }
}

__global__ __launch_bounds__(256) void scan3_k(const int* __restrict__ cnt,
                                               const int* __restrict__ inv,
                                               const int* __restrict__ bsum,
                                               const int* __restrict__ bsumI,
                                               int* __restrict__ offsets,
                                               int* __restrict__ ccur,
                                               int* __restrict__ ilist, int N) {
    __shared__ int s[256];
    const int b = blockIdx.x, tid = threadIdx.x;
    const int base = b * CHUNK + tid * 8;

    // phase A: cnt -> offsets (+ coarse bases for coarse_bin)
    int v[8]; int tsum = 0;
#pragma unroll
    for (int j = 0; j < 8; ++j) {
        int t = (base + j < N) ? cnt[base + j] : 0;
        v[j] = tsum; tsum += t;
    }
    s[tid] = tsum;
    __syncthreads();
    for (int st = 1; st < 256; st <<= 1) {
        int val = (tid >= st) ? s[tid - st] : 0;
        __syncthreads();
        s[tid] += val;
        __syncthreads();
    }
    const int texcl = s[tid] - tsum + bsum[b];
#pragma unroll
    for (int j = 0; j < 8; ++j) {
        int i = base + j;
        if (i < N) {
            int o = texcl + v[j];
            offsets[i] = o;
            if ((i & (BSZ - 1)) == 0) ccur[i >> BSH] = o;
        }
    }
    __syncthreads();

    // phase B: inv -> ordered ilist
    int vi[8]; int tsumi = 0;
#pragma unroll
    for (int j = 0; j < 8; ++j) {
        int t = (base + j < N) ? inv[base + j] : 0;
        vi[j] = tsumi; tsumi += t;
    }
    s[tid] = tsumi;
    __syncthreads();
    for (int st = 1; st < 256; st <<= 1) {
        int val = (tid >= st) ? s[tid - st] : 0;
        __syncthreads();
        s[tid] += val;
        __syncthreads();
    }
    const int texclI = s[tid] - tsumi + bsumI[b];
#pragma unroll
    for (int j = 0; j < 8; ++j) {
        int i = base + j;
        if (i < N && inv[i]) ilist[texclI + vi[j]] = i;
    }
}

// coarse pass: bin edges by dst>>BSH; block-local LDS hist + one reservation
// atomic per (block,bucket); entry = (dloc<<18)|(src<<1)|r  (fits: src<2^17)
__global__ __launch_bounds__(256) void coarse_bin_k(
    const int* __restrict__ src, const int* __restrict__ dst,
    const int* __restrict__ r,
    int* __restrict__ ccur, unsigned* __restrict__ ebuf, int E)
{
    __shared__ int hcnt[256];
    __shared__ int gbase[256];
    __shared__ int lcur[256];
    const int tid = threadIdx.x;
    hcnt[tid] = 0;
    __syncthreads();
    const int base = blockIdx.x * ACH;
    unsigned v[8]; int bk[8];
#pragma unroll
    for (int j = 0; j < 8; ++j) {
        const int e = base + j * 256 + tid;
        if (e < E) {
            const int d = dst[e];
            bk[j] = d >> BSH;
            v[j] = ((unsigned)(d & (BSZ - 1)) << 18) |
                   ((unsigned)src[e] << 1) | (unsigned)r[e];
            atomicAdd(&hcnt[bk[j]], 1);
        } else bk[j] = -1;
    }
    __syncthreads();
    const int c = hcnt[tid];
    gbase[tid] = (c > 0) ? atomicAdd(&ccur[tid], c) : 0;
    lcur[tid] = 0;
    __syncthreads();
#pragma unroll
    for (int j = 0; j < 8; ++j) {
        if (bk[j] >= 0) {
            const int loc = atomicAdd(&lcur[bk[j]], 1);
            ebuf[gbase[bk[j]] + loc] = v[j];
        }
    }
}

// fine pass: one block per 512-node bucket; LDS cursors; 16KB output region
// stays in a single XCD's L2 -> writeback ~1x
__global__ __launch_bounds__(256) void fine_scatter_k(
    const unsigned* __restrict__ ebuf, const int* __restrict__ offsets,
    int* __restrict__ packed, int N, int E)
{
    __shared__ int cur[BSZ];
    const int b  = blockIdx.x;
    const int lo = b << BSH;
    const int hi = min(lo + BSZ, N);
    for (int i = threadIdx.x; i < hi - lo; i += 256) cur[i] = offsets[lo + i];
    __syncthreads();
    const int rstart = offsets[lo];
    const int rend   = (hi == N) ? E : offsets[hi];
    for (int i = rstart + threadIdx.x; i < rend; i += 256) {
        const unsigned v = ebuf[i];
        const int dloc = v >> 18;
        const int pos = atomicAdd(&cur[dloc], 1);
        packed[pos] = (int)(((v & 0x3ffffu) >> 1) | ((v & 1u) << 31));
    }
}

// one wave per node: 4 rows x 16 lanes x 16B per load group, 8 rows in flight;
// f32 accum; shfl_xor(16,32) combine; bf16 mean out
__global__ __launch_bounds__(256) void gather_mean_k(
    const ushort_t* __restrict__ featb, const ushort_t* __restrict__ invb,
    const int* __restrict__ offsets, const int* __restrict__ cnt,
    const int* __restrict__ packed, ushort_t* __restrict__ neighb, int N)
{
    const int wv = threadIdx.x >> 6, lane = threadIdx.x & 63;
    const int n = blockIdx.x * 4 + wv;
    if (n >= N) return;
    const int start = offsets[n];
    const int d = cnt[n];
    const int q4 = lane >> 4;                    // row-in-group 0..3
    const size_t co = (size_t)(lane & 15) * 8;   // col base
    float a[8] = {0.f, 0.f, 0.f, 0.f, 0.f, 0.f, 0.f, 0.f};
    int k = 0;
    for (; k + 7 < d; k += 8) {
        const int pA = packed[start + k + q4];
        const int pB = packed[start + k + 4 + q4];
        const ushort_t* tA = (pA < 0) ? invb : featb;
        const ushort_t* tB = (pB < 0) ? invb : featb;
        const us8 uA = *(const us8*)(tA + (size_t)(pA & 0x7fffffff) * H + co);
        const us8 uB = *(const us8*)(tB + (size_t)(pB & 0x7fffffff) * H + co);
#pragma unroll
        for (int i = 0; i < 8; ++i) a[i] += bfl(uA[i]) + bfl(uB[i]);
    }
    if (k + 3 < d) {
        const int p = packed[start + k + q4];
        const ushort_t* t = (p < 0) ? invb : featb;
        const us8 u = *(const us8*)(t + (size_t)(p & 0x7fffffff) * H + co);
#pragma unroll
        for (int i = 0; i < 8; ++i) a[i] += bfl(u[i]);
        k += 4;
    }
    const int rem = d - k;
    if (q4 < rem) {
        const int p = packed[start + k + q4];
        const ushort_t* t = (p < 0) ? invb : featb;
        const us8 u = *(const us8*)(t + (size_t)(p & 0x7fffffff) * H + co);
#pragma unroll
        for (int i = 0; i < 8; ++i) a[i] += bfl(u[i]);
    }
#pragma unroll
    for (int i = 0; i < 8; ++i) {
        a[i] += __shfl_xor(a[i], 16);
        a[i] += __shfl_xor(a[i], 32);
    }
    if (q4 == 0) {
        const float scl = 1.0f / (float)max(d, 1);
        us8 o;
#pragma unroll
        for (int i = 0; i < 8; ++i) o[i] = bfbits(a[i] * scl);
        *(us8*)(neighb + (size_t)n * H + co) = o;
    }
}

extern "C" void kernel_launch(void* const* d_in, const int* in_sizes, int n_in,
                              void* d_out, int out_size, void* d_ws, size_t ws_size,
                              hipStream_t stream) {
    const float* feat = (const float*)d_in[0];
    const int*   src  = (const int*)d_in[1];
    const int*   dst  = (const int*)d_in[2];
    const int*   r    = (const int*)d_in[3];
    const int*   inv  = (const int*)d_in[4];
    const float* iw1 = (const float*)d_in[5],  *ib1 = (const float*)d_in[6];
    const float* iw2 = (const float*)d_in[7],  *ib2 = (const float*)d_in[8];
    const float* iw3 = (const float*)d_in[9],  *ib3 = (const float*)d_in[10];
    const float* aw1 = (const float*)d_in[11], *ab1 = (const float*)d_in[12];
    const float* aw2 = (const float*)d_in[13], *ab2 = (const float*)d_in[14];
    const float* aw3 = (const float*)d_in[15], *ab3 = (const float*)d_in[16];

    const int N = in_sizes[4];   // inv is [N]
    const int E = in_sizes[1];   // src is [E]

    ushort_t* featb  = (ushort_t*)d_ws;             // N*H bf16
    ushort_t* invb   = featb + (size_t)N * H;       // N*H bf16
    ushort_t* neighb = invb + (size_t)N * H;        // N*H bf16
    int* cnt     = (int*)(neighb + (size_t)N * H);
    int* offsets = cnt + N;
    int* ilist   = offsets + N;
    unsigned* ebuf = (unsigned*)(ilist + N);
    int* packed  = (int*)(ebuf + E);
    int* bsum    = packed + E;
    int* bsumI   = bsum + 256;
    int* icnt    = bsumI + 256;
    int* ccur    = icnt + 1;

    const int nchunks = (N + CHUNK - 1) / CHUNK;
    const int ntiles  = (N + 15) / 16;
    const int NB      = (N + BSZ - 1) / BSZ;        // coarse buckets (<=256)
    const int g1      = min((ntiles + NW - 1) / NW, 512);  // 2 blocks/CU

    hipMemsetAsync(cnt, 0, (size_t)N * sizeof(int), stream);

    // 1) invb = bf16(mlp_inv(feat)); featb = bf16(feat)
    mlp3_t<false, true, true, false><<<g1, 512, 0, stream>>>(
        feat, iw1, ib1, iw2, ib2, iw3, ib3, invb, featb, nullptr, nullptr, N, ntiles);
    // 2) CSR build: hist -> scan (offsets, ilist, coarse bases) -> 2-level sort
    hist_k<<<(E + 255) / 256, 256, 0, stream>>>(dst, cnt, E);
    scan1_k<<<nchunks, 256, 0, stream>>>(cnt, inv, bsum, bsumI, N);
    scan2_k<<<1, 64, 0, stream>>>(bsum, bsumI, icnt, nchunks);
    scan3_k<<<nchunks, 256, 0, stream>>>(cnt, inv, bsum, bsumI, offsets, ccur, ilist, N);
    coarse_bin_k<<<(E + ACH - 1) / ACH, 256, 0, stream>>>(src, dst, r, ccur, ebuf, E);
    fine_scatter_k<<<NB, 256, 0, stream>>>(ebuf, offsets, packed, N, E);
    // 3) neighb = bf16(mean of messages)
    gather_mean_k<<<(N + 3) / 4, 256, 0, stream>>>(featb, invb, offsets, cnt,
                                                   packed, neighb, N);
    // 4) d_out = mlp_and(neighb)  (f32, all rows)
    mlp3_t<true, false, false, false><<<g1, 512, 0, stream>>>(
        neighb, aw1, ab1, aw2, ab2, aw3, ab3, d_out, nullptr, nullptr, nullptr, N, ntiles);
    // 5) d_out[ilist] = mlp_inv(d_out[ilist])  (sparse, ~50% of rows)
    mlp3_t<false, false, false, true><<<256, 512, 0, stream>>>(
        d_out, iw1, ib1, iw2, ib2, iw3, ib3, d_out, nullptr, ilist, icnt, N, ntiles);
}

// Round 6
// 164.998 us; speedup vs baseline: 9.3398x; 1.1726x over previous
//
#include <hip/hip_runtime.h>

// FuncConv: out = select(inv, mlp_inv(res), res); res = mlp_and(mean_dst(msg));
// msg = select(r, mlp_inv(feat[src]), feat[src]).
// R5: (a) CSR chain: coarse histogram (196 bins) + 1-block scan + coarse_bin +
//     fine_build (per-bucket LDS hist/scan emits offsets+packed) — replaces
//     hist_k (800k random atomics) + 3-kernel global scan for offsets;
// (b) pass4 SPLIT: non-inv rows f32 -> d_out, inv rows bf16 rank-compacted ->
//     resb (aliases dead featb); pass5 reads resb sequentially (bf16);
// (c) gather: deg from offsets diff, 16-deep row unroll.
//
// ws: featb[N*H bf16 | resb aliases] invb[N*H bf16] neighb[N*H bf16]
//     offsets[N+1] ilist[N] irank[N] ebuf[E] packed[E]
//     chist[256] cbase[257] ccur[256] bsumI[256] icnt[1]

#define H 128
#define HH 64
#define CHUNK 2048
#define NW 8      // waves per MLP block
#define BSH 9     // log2 nodes per coarse bucket
#define BSZ 512   // nodes per coarse bucket
#define ACH 2048  // edges per coarse block

typedef float f32x4 __attribute__((ext_vector_type(4)));
typedef __bf16 bf16x8 __attribute__((ext_vector_type(8)));
typedef unsigned short us8 __attribute__((ext_vector_type(8)));
typedef unsigned short ushort_t;

__device__ __forceinline__ unsigned short bfbits(float f) {
    __bf16 h = (__bf16)f;                       // RNE convert
    return __builtin_bit_cast(unsigned short, h);
}
__device__ __forceinline__ bf16x8 as_bf16x8(us8 v) {
    return __builtin_bit_cast(bf16x8, v);
}
__device__ __forceinline__ float bfl(unsigned short u) {
    return __builtin_bit_cast(float, ((unsigned)u) << 16);
}

// per-wave transpose buffer: 16 rows x 64 cols bf16, XOR-swizzled
__device__ __forceinline__ int tb_off(int m, int j) {
    return m * 64 + ((((j * 2) ^ ((m & 7) << 4))) >> 1);
}
__device__ __forceinline__ bf16x8 ld_tb(const unsigned short* tb, int m, int j0) {
    return as_bf16x8(*(const us8*)&tb[tb_off(m, j0)]);
}
__device__ __forceinline__ bf16x8 ld_fr(const unsigned short* FR, int fid, int lane) {
    return as_bf16x8(*(const us8*)&FR[(fid * 64 + lane) * 8]);
}

// ---------------- fused 3-layer MLP, persistent blocks -----------------------
// INB:   X is bf16 row-major, else f32
// OUTB:  OUT is bf16 (staged through LDS, coalesced)
// WF:    also write bf16 copy of X to xtra (requires !INB)
// LIST:  input row = pos (compact), output row = rows[pos], count rowcnt[0]
// SPLIT: out rows with invp==0 -> f32 OUT; invp==1 -> bf16 xtra[irank[row]]
template<bool INB, bool OUTB, bool WF, bool LIST, bool SPLIT>
__global__ __launch_bounds__(512, 4) void mlp3_t(
    const void* X_,
    const float* __restrict__ W1, const float* __restrict__ B1,
    const float* __restrict__ W2, const float* __restrict__ B2,
    const float* __restrict__ W3, const float* __restrict__ B3,
    void* OUT_,
    ushort_t* __restrict__ xtra,
    const int* __restrict__ rows, const int* __restrict__ rowcnt,
    const int* __restrict__ invp, const int* __restrict__ irank,
    int nrows, int ntiles)
{
    __shared__ __align__(16) unsigned short FR[40 * 64 * 8];    // 40 KB
    __shared__ __align__(16) unsigned short TBs[NW * 16 * 64];  // 16 KB
    const float*    Xf = (const float*)X_;
    const ushort_t* Xb = (const ushort_t*)X_;

    const int tid  = threadIdx.x;
    const int wv   = tid >> 6;
    const int lane = tid & 63;
    const int ln   = lane & 15;
    const int hi   = lane >> 4;

    for (int fid = wv; fid < 40; fid += NW) {
        const float* w; int inF, s, t;
        if (fid < 16)      { w = W1; inF = H;  s = fid >> 2;        t = fid & 3; }
        else if (fid < 24) { w = W2; inF = HH; s = (fid - 16) >> 2; t = (fid - 16) & 3; }
        else               { w = W3; inF = HH; s = (fid - 24) >> 3; t = (fid - 24) & 7; }
        const float* p = w + (size_t)(t * 16 + ln) * inF + (s * 32 + hi * 8);
        f32x4 a = *(const f32x4*)p;
        f32x4 b = *(const f32x4*)(p + 4);
        unsigned short* d = &FR[(fid * 64 + lane) * 8];
        d[0] = bfbits(a[0]); d[1] = bfbits(a[1]); d[2] = bfbits(a[2]); d[3] = bfbits(a[3]);
        d[4] = bfbits(b[0]); d[5] = bfbits(b[1]); d[6] = bfbits(b[2]); d[7] = bfbits(b[3]);
    }
    float b1r[4], b2r[4], b3r[8];
#pragma unroll
    for (int t = 0; t < 4; ++t) b1r[t] = B1[t * 16 + ln];
#pragma unroll
    for (int t = 0; t < 4; ++t) b2r[t] = B2[t * 16 + ln];
#pragma unroll
    for (int t = 0; t < 8; ++t) b3r[t] = B3[t * 16 + ln];
    __syncthreads();

    int rcnt, tcount;
    if constexpr (LIST) { rcnt = rowcnt[0]; tcount = (rcnt + 15) >> 4; }
    else                { rcnt = nrows;     tcount = ntiles; }

    unsigned short* tb = &TBs[wv * 16 * 64];

    for (int tile = blockIdx.x * NW + wv; tile < tcount; tile += gridDim.x * NW) {
        const int node0 = tile * 16;
        const int lpos  = min(node0 + ln, rcnt - 1);
        const int arow  = lpos;                    // LIST input is compact
        const size_t ro = (size_t)arow * H;

        bf16x8 a1[4];
#pragma unroll
        for (int s = 0; s < 4; ++s) {
            if constexpr (INB) {
                a1[s] = as_bf16x8(*(const us8*)(Xb + ro + s * 32 + hi * 8));
            } else {
                f32x4 u = *(const f32x4*)(Xf + ro + s * 32 + hi * 8);
                f32x4 v = *(const f32x4*)(Xf + ro + s * 32 + hi * 8 + 4);
                bf16x8 f;
                f[0] = (__bf16)u[0]; f[1] = (__bf16)u[1]; f[2] = (__bf16)u[2]; f[3] = (__bf16)u[3];
                f[4] = (__bf16)v[0]; f[5] = (__bf16)v[1]; f[6] = (__bf16)v[2]; f[7] = (__bf16)v[3];
                a1[s] = f;
                if constexpr (WF)
                    *(us8*)(xtra + ro + s * 32 + hi * 8) = __builtin_bit_cast(us8, f);
            }
        }

        // layer 1
#pragma unroll
        for (int t = 0; t < 4; ++t) {
            f32x4 acc = {0.f, 0.f, 0.f, 0.f};
#pragma unroll
            for (int s = 0; s < 4; ++s)
                acc = __builtin_amdgcn_mfma_f32_16x16x32_bf16(a1[s], ld_fr(FR, s * 4 + t, lane), acc, 0, 0, 0);
#pragma unroll
            for (int q = 0; q < 4; ++q) {
                float y = acc[q] + b1r[t];
                y = (y >= 0.f) ? y : 0.01f * y;
                tb[tb_off(hi * 4 + q, t * 16 + ln)] = bfbits(y);
            }
        }

        // layer 2
        bf16x8 a2[2];
#pragma unroll
        for (int s = 0; s < 2; ++s) a2[s] = ld_tb(tb, ln, s * 32 + hi * 8);
#pragma unroll
        for (int t = 0; t < 4; ++t) {
            f32x4 acc = {0.f, 0.f, 0.f, 0.f};
#pragma unroll
            for (int s = 0; s < 2; ++s)
                acc = __builtin_amdgcn_mfma_f32_16x16x32_bf16(a2[s], ld_fr(FR, 16 + s * 4 + t, lane), acc, 0, 0, 0);
#pragma unroll
            for (int q = 0; q < 4; ++q) {
                float y = acc[q] + b2r[t];
                y = (y >= 0.f) ? y : 0.01f * y;
                tb[tb_off(hi * 4 + q, t * 16 + ln)] = bfbits(y);
            }
        }

        // layer 3
        bf16x8 a3[2];
#pragma unroll
        for (int s = 0; s < 2; ++s) a3[s] = ld_tb(tb, ln, s * 32 + hi * 8);

        if constexpr (OUTB) {
            ushort_t* OUTb = (ushort_t*)OUT_;
#pragma unroll
            for (int half = 0; half < 2; ++half) {
#pragma unroll
                for (int t2 = 0; t2 < 4; ++t2) {
                    const int t = half * 4 + t2;
                    f32x4 acc = {0.f, 0.f, 0.f, 0.f};
#pragma unroll
                    for (int s = 0; s < 2; ++s)
                        acc = __builtin_amdgcn_mfma_f32_16x16x32_bf16(a3[s], ld_fr(FR, 24 + s * 8 + t, lane), acc, 0, 0, 0);
#pragma unroll
                    for (int q = 0; q < 4; ++q)
                        tb[tb_off(hi * 4 + q, t2 * 16 + ln)] = bfbits(acc[q] + b3r[t]);
                }
                const int rr = lane >> 2, c0 = (lane & 3) * 16;
                if (node0 + rr < rcnt) {
                    us8 w0 = __builtin_bit_cast(us8, ld_tb(tb, rr, c0));
                    us8 w1 = __builtin_bit_cast(us8, ld_tb(tb, rr, c0 + 8));
                    ushort_t* op = OUTb + (size_t)(node0 + rr) * H + half * 64 + c0;
                    *(us8*)op = w0;
                    *(us8*)(op + 8) = w1;
                }
            }
        } else if constexpr (SPLIT) {
            float* OUTf = (float*)OUT_;
            int iq[4];
#pragma unroll
            for (int q = 0; q < 4; ++q) {
                const int row = node0 + hi * 4 + q;
                iq[q] = (row < rcnt) ? invp[row] : 1;
            }
            const int rr = lane >> 2, c0 = (lane & 3) * 16;
            const int rowrr = node0 + rr;
            const bool winv = (rowrr < rcnt) && (invp[rowrr] != 0);
            const int irk = winv ? irank[rowrr] : 0;
#pragma unroll
            for (int half = 0; half < 2; ++half) {
#pragma unroll
                for (int t2 = 0; t2 < 4; ++t2) {
                    const int t = half * 4 + t2;
                    f32x4 acc = {0.f, 0.f, 0.f, 0.f};
#pragma unroll
                    for (int s = 0; s < 2; ++s)
                        acc = __builtin_amdgcn_mfma_f32_16x16x32_bf16(a3[s], ld_fr(FR, 24 + s * 8 + t, lane), acc, 0, 0, 0);
#pragma unroll
                    for (int q = 0; q < 4; ++q) {
                        const float y = acc[q] + b3r[t];
                        tb[tb_off(hi * 4 + q, t2 * 16 + ln)] = bfbits(y);
                        const int row = node0 + hi * 4 + q;
                        if (row < rcnt && !iq[q])
                            OUTf[(size_t)row * H + half * 64 + t2 * 16 + ln] = y;
                    }
                }
                if (winv) {
                    us8 w0 = __builtin_bit_cast(us8, ld_tb(tb, rr, c0));
                    us8 w1 = __builtin_bit_cast(us8, ld_tb(tb, rr, c0 + 8));
                    ushort_t* op = xtra + (size_t)irk * H + half * 64 + c0;
                    *(us8*)op = w0;
                    *(us8*)(op + 8) = w1;
                }
            }
        } else {
            float* OUTf = (float*)OUT_;
            int grow[4];
#pragma unroll
            for (int q = 0; q < 4; ++q) {
                const int pos = node0 + hi * 4 + q;
                grow[q] = (pos < rcnt) ? (LIST ? rows[pos] : pos) : -1;
            }
#pragma unroll
            for (int t = 0; t < 8; ++t) {
                f32x4 acc = {0.f, 0.f, 0.f, 0.f};
#pragma unroll
                for (int s = 0; s < 2; ++s)
                    acc = __builtin_amdgcn_mfma_f32_16x16x32_bf16(a3[s], ld_fr(FR, 24 + s * 8 + t, lane), acc, 0, 0, 0);
#pragma unroll
                for (int q = 0; q < 4; ++q) {
                    if (grow[q] >= 0)
                        OUTf[(size_t)grow[q] * H + t * 16 + ln] = acc[q] + b3r[t];
                }
            }
        }
    }
}

// ---------------- CSR build (two-level counting sort by dst) -----------------
__global__ __launch_bounds__(256) void coarse_hist_k(const int* __restrict__ dst,
                                                     int* __restrict__ chist, int E) {
    __shared__ int h[256];
    const int tid = threadIdx.x;
    h[tid] = 0;
    __syncthreads();
    const int base = blockIdx.x * ACH;
#pragma unroll
    for (int j = 0; j < 8; ++j) {
        const int e = base + j * 256 + tid;
        if (e < E) atomicAdd(&h[dst[e] >> BSH], 1);
    }
    __syncthreads();
    if (h[tid]) atomicAdd(&chist[tid], h[tid]);
}

__global__ __launch_bounds__(256) void cscan_k(const int* __restrict__ chist,
                                               int* __restrict__ cbase,
                                               int* __restrict__ ccur, int nb, int E) {
    __shared__ int s[256];
    const int tid = threadIdx.x;
    const int v = (tid < nb) ? chist[tid] : 0;
    s[tid] = v;
    __syncthreads();
    for (int st = 1; st < 256; st <<= 1) {
        int t = (tid >= st) ? s[tid - st] : 0;
        __syncthreads();
        s[tid] += t;
        __syncthreads();
    }
    const int excl = s[tid] - v;
    if (tid < nb) { cbase[tid] = excl; ccur[tid] = excl; }
    if (tid == 0) cbase[nb] = E;
}

// coarse pass: bin edges by dst>>BSH; block-local LDS hist + one reservation
// atomic per (block,bucket); entry = (dloc<<18)|(src<<1)|r  (src < 2^17)
__global__ __launch_bounds__(256) void coarse_bin_k(
    const int* __restrict__ src, const int* __restrict__ dst,
    const int* __restrict__ r,
    int* __restrict__ ccur, unsigned* __restrict__ ebuf, int E)
{
    __shared__ int hcnt[256];
    __shared__ int gbase[256];
    __shared__ int lcur[256];
    const int tid = threadIdx.x;
    hcnt[tid] = 0;
    __syncthreads();
    const int base = blockIdx.x * ACH;
    unsigned v[8]; int bk[8];
#pragma unroll
    for (int j = 0; j < 8; ++j) {
        const int e = base + j * 256 + tid;
        if (e < E) {
            const int d = dst[e];
            bk[j] = d >> BSH;
            v[j] = ((unsigned)(d & (BSZ - 1)) << 18) |
                   ((unsigned)src[e] << 1) | (unsigned)r[e];
            atomicAdd(&hcnt[bk[j]], 1);
        } else bk[j] = -1;
    }
    __syncthreads();
    const int c = hcnt[tid];
    gbase[tid] = (c > 0) ? atomicAdd(&ccur[tid], c) : 0;
    lcur[tid] = 0;
    __syncthreads();
#pragma unroll
    for (int j = 0; j < 8; ++j) {
        if (bk[j] >= 0) {
            const int loc = atomicAdd(&lcur[bk[j]], 1);
            ebuf[gbase[bk[j]] + loc] = v[j];
        }
    }
}

// fine pass: one block per 512-node bucket. LDS hist + LDS scan emit offsets;
// LDS cursors scatter packed. Output region ~16KB stays in one XCD L2.
__global__ __launch_bounds__(512) void fine_build_k(
    const unsigned* __restrict__ ebuf, const int* __restrict__ cbase,
    int* __restrict__ offsets, int* __restrict__ packed, int N, int E, int nb)
{
    __shared__ int loff[BSZ];
    __shared__ int lcur[BSZ];
    const int b = blockIdx.x, tid = threadIdx.x;
    const int lo = b << BSH;
    const int nn = min(BSZ, N - lo);
    const int rstart = cbase[b];
    const int rend   = cbase[b + 1];
    lcur[tid] = 0;
    __syncthreads();
    for (int i = rstart + tid; i < rend; i += BSZ)
        atomicAdd(&lcur[ebuf[i] >> 18], 1);
    __syncthreads();
    const int v = lcur[tid];
    loff[tid] = v;
    __syncthreads();
    for (int st = 1; st < BSZ; st <<= 1) {
        int t = (tid >= st) ? loff[tid - st] : 0;
        __syncthreads();
        loff[tid] += t;
        __syncthreads();
    }
    const int base = rstart + loff[tid] - v;     // exclusive prefix
    if (tid < nn) offsets[lo + tid] = base;
    if (b == nb - 1 && tid == 0) offsets[N] = E;
    __syncthreads();
    lcur[tid] = base;
    __syncthreads();
    for (int i = rstart + tid; i < rend; i += BSZ) {
        const unsigned w = ebuf[i];
        const int dloc = w >> 18;
        const int pos = atomicAdd(&lcur[dloc], 1);
        packed[pos] = (int)(((w & 0x3ffffu) >> 1) | ((w & 1u) << 31));
    }
}

// ---------------- inv scan: ilist (ordered) + irank ---------------------------
__global__ __launch_bounds__(256) void iscan1_k(const int* __restrict__ inv,
                                                int* __restrict__ bsumI, int N) {
    __shared__ int si[256];
    const int b = blockIdx.x, tid = threadIdx.x;
    const int base = b * CHUNK + tid * 8;
    int sumi = 0;
#pragma unroll
    for (int j = 0; j < 8; ++j) { int i = base + j; if (i < N) sumi += inv[i]; }
    si[tid] = sumi;
    __syncthreads();
    for (int st = 128; st > 0; st >>= 1) {
        if (tid < st) si[tid] += si[tid + st];
        __syncthreads();
    }
    if (tid == 0) bsumI[b] = si[0];
}

__global__ void iscan2_k(int* bsumI, int* icnt, int nchunks) {
    const int lane = threadIdx.x;
    if (nchunks <= 64) {
        int u = (lane < nchunks) ? bsumI[lane] : 0;
        int ou = u;
        for (int st = 1; st < 64; st <<= 1) { int w = __shfl_up(u, st); if (lane >= st) u += w; }
        if (lane < nchunks) bsumI[lane] = u - ou;
        if (lane == 63) icnt[0] = u;
    } else if (lane == 0) {
        int runi = 0;
        for (int i = 0; i < nchunks; ++i) { int u = bsumI[i]; bsumI[i] = runi; runi += u; }
        icnt[0] = runi;
    }
}

__global__ __launch_bounds__(256) void iscan3_k(const int* __restrict__ inv,
                                                const int* __restrict__ bsumI,
                                                int* __restrict__ ilist,
                                                int* __restrict__ irank, int N) {
    __shared__ int s[256];
    const int b = blockIdx.x, tid = threadIdx.x;
    const int base = b * CHUNK + tid * 8;
    int vi[8]; int tsumi = 0;
#pragma unroll
    for (int j = 0; j < 8; ++j) {
        int t = (base + j < N) ? inv[base + j] : 0;
        vi[j] = tsumi; tsumi += t;
    }
    s[tid] = tsumi;
    __syncthreads();
    for (int st = 1; st < 256; st <<= 1) {
        int val = (tid >= st) ? s[tid - st] : 0;
        __syncthreads();
        s[tid] += val;
        __syncthreads();
    }
    const int texclI = s[tid] - tsumi + bsumI[b];
#pragma unroll
    for (int j = 0; j < 8; ++j) {
        int i = base + j;
        if (i < N && inv[i]) {
            const int rank = texclI + vi[j];
            ilist[rank] = i;
            irank[i] = rank;
        }
    }
}

// one wave per node: 4 rows x 16 lanes x 16B, 16 rows in flight; f32 accum;
// shfl_xor(16,32) combine; bf16 mean out. deg = offsets diff.
__global__ __launch_bounds__(256) void gather_mean_k(
    const ushort_t* __restrict__ featb, const ushort_t* __restrict__ invb,
    const int* __restrict__ offsets,
    const int* __restrict__ packed, ushort_t* __restrict__ neighb, int N)
{
    const int wv = threadIdx.x >> 6, lane = threadIdx.x & 63;
    const int n = blockIdx.x * 4 + wv;
    if (n >= N) return;
    const int start = offsets[n];
    const int d = offsets[n + 1] - start;
    const int q4 = lane >> 4;                    // row-in-group 0..3
    const size_t co = (size_t)(lane & 15) * 8;   // col base
    float a[8] = {0.f, 0.f, 0.f, 0.f, 0.f, 0.f, 0.f, 0.f};
    int k = 0;
    for (; k + 15 < d; k += 16) {
        const int p0 = packed[start + k + q4];
        const int p1 = packed[start + k + 4 + q4];
        const int p2 = packed[start + k + 8 + q4];
        const int p3 = packed[start + k + 12 + q4];
        const ushort_t* t0 = (p0 < 0) ? invb : featb;
        const ushort_t* t1 = (p1 < 0) ? invb : featb;
        const ushort_t* t2 = (p2 < 0) ? invb : featb;
        const ushort_t* t3 = (p3 < 0) ? invb : featb;
        const us8 u0 = *(const us8*)(t0 + (size_t)(p0 & 0x7fffffff) * H + co);
        const us8 u1 = *(const us8*)(t1 + (size_t)(p1 & 0x7fffffff) * H + co);
        const us8 u2 = *(const us8*)(t2 + (size_t)(p2 & 0x7fffffff) * H + co);
        const us8 u3 = *(const us8*)(t3 + (size_t)(p3 & 0x7fffffff) * H + co);
#pragma unroll
        for (int i = 0; i < 8; ++i) a[i] += (bfl(u0[i]) + bfl(u1[i])) + (bfl(u2[i]) + bfl(u3[i]));
    }
    for (; k + 7 < d; k += 8) {
        const int pA = packed[start + k + q4];
        const int pB = packed[start + k + 4 + q4];
        const ushort_t* tA = (pA < 0) ? invb : featb;
        const ushort_t* tB = (pB < 0) ? invb : featb;
        const us8 uA = *(const us8*)(tA + (size_t)(pA & 0x7fffffff) * H + co);
        const us8 uB = *(const us8*)(tB + (size_t)(pB & 0x7fffffff) * H + co);
#pragma unroll
        for (int i = 0; i < 8; ++i) a[i] += bfl(uA[i]) + bfl(uB[i]);
    }
    if (k + 3 < d) {
        const int p = packed[start + k + q4];
        const ushort_t* t = (p < 0) ? invb : featb;
        const us8 u = *(const us8*)(t + (size_t)(p & 0x7fffffff) * H + co);
#pragma unroll
        for (int i = 0; i < 8; ++i) a[i] += bfl(u[i]);
        k += 4;
    }
    const int rem = d - k;
    if (q4 < rem) {
        const int p = packed[start + k + q4];
        const ushort_t* t = (p < 0) ? invb : featb;
        const us8 u = *(const us8*)(t + (size_t)(p & 0x7fffffff) * H + co);
#pragma unroll
        for (int i = 0; i < 8; ++i) a[i] += bfl(u[i]);
    }
#pragma unroll
    for (int i = 0; i < 8; ++i) {
        a[i] += __shfl_xor(a[i], 16);
        a[i] += __shfl_xor(a[i], 32);
    }
    if (q4 == 0) {
        const float scl = 1.0f / (float)max(d, 1);
        us8 o;
#pragma unroll
        for (int i = 0; i < 8; ++i) o[i] = bfbits(a[i] * scl);
        *(us8*)(neighb + (size_t)n * H + co) = o;
    }
}

extern "C" void kernel_launch(void* const* d_in, const int* in_sizes, int n_in,
                              void* d_out, int out_size, void* d_ws, size_t ws_size,
                              hipStream_t stream) {
    const float* feat = (const float*)d_in[0];
    const int*   src  = (const int*)d_in[1];
    const int*   dst  = (const int*)d_in[2];
    const int*   r    = (const int*)d_in[3];
    const int*   inv  = (const int*)d_in[4];
    const float* iw1 = (const float*)d_in[5],  *ib1 = (const float*)d_in[6];
    const float* iw2 = (const float*)d_in[7],  *ib2 = (const float*)d_in[8];
    const float* iw3 = (const float*)d_in[9],  *ib3 = (const float*)d_in[10];
    const float* aw1 = (const float*)d_in[11], *ab1 = (const float*)d_in[12];
    const float* aw2 = (const float*)d_in[13], *ab2 = (const float*)d_in[14];
    const float* aw3 = (const float*)d_in[15], *ab3 = (const float*)d_in[16];

    const int N = in_sizes[4];   // inv is [N]
    const int E = in_sizes[1];   // src is [E]

    ushort_t* featb  = (ushort_t*)d_ws;             // N*H bf16; dead after gather
    ushort_t* resb   = featb;                       //   ...aliased by resb (pass4/5)
    ushort_t* invb   = featb + (size_t)N * H;       // N*H bf16
    ushort_t* neighb = invb + (size_t)N * H;        // N*H bf16
    int* offsets = (int*)(neighb + (size_t)N * H);  // N+1
    int* ilist   = offsets + (N + 1);
    int* irank   = ilist + N;
    unsigned* ebuf = (unsigned*)(irank + N);
    int* packed  = (int*)(ebuf + E);
    int* chist   = packed + E;
    int* cbase   = chist + 256;                     // 257
    int* ccur    = cbase + 257;
    int* bsumI   = ccur + 256;
    int* icnt    = bsumI + 256;

    const int nchunks = (N + CHUNK - 1) / CHUNK;
    const int ntiles  = (N + 15) / 16;
    const int NB      = (N + BSZ - 1) / BSZ;        // coarse buckets (<=256)
    const int cgrid   = (E + ACH - 1) / ACH;
    const int g1      = min((ntiles + NW - 1) / NW, 512);  // 2 blocks/CU

    hipMemsetAsync(chist, 0, 256 * sizeof(int), stream);

    // 1) invb = bf16(mlp_inv(feat)); featb = bf16(feat)
    mlp3_t<false, true, true, false, false><<<g1, 512, 0, stream>>>(
        feat, iw1, ib1, iw2, ib2, iw3, ib3, invb, featb,
        nullptr, nullptr, nullptr, nullptr, N, ntiles);
    // 2) CSR build: coarse hist -> tiny scan -> coarse bin -> fine build
    coarse_hist_k<<<cgrid, 256, 0, stream>>>(dst, chist, E);
    cscan_k<<<1, 256, 0, stream>>>(chist, cbase, ccur, NB, E);
    coarse_bin_k<<<cgrid, 256, 0, stream>>>(src, dst, r, ccur, ebuf, E);
    fine_build_k<<<NB, BSZ, 0, stream>>>(ebuf, cbase, offsets, packed, N, E, NB);
    // 2b) inv scan -> ilist (ordered) + irank
    iscan1_k<<<nchunks, 256, 0, stream>>>(inv, bsumI, N);
    iscan2_k<<<1, 64, 0, stream>>>(bsumI, icnt, nchunks);
    iscan3_k<<<nchunks, 256, 0, stream>>>(inv, bsumI, ilist, irank, N);
    // 3) neighb = bf16(mean of messages)
    gather_mean_k<<<(N + 3) / 4, 256, 0, stream>>>(featb, invb, offsets,
                                                   packed, neighb, N);
    // 4) res = mlp_and(neighb): non-inv rows f32 -> d_out, inv rows bf16 -> resb
    mlp3_t<true, false, false, false, true><<<g1, 512, 0, stream>>>(
        neighb, aw1, ab1, aw2, ab2, aw3, ab3, d_out, resb,
        nullptr, nullptr, inv, irank, N, ntiles);
    // 5) d_out[ilist] = mlp_inv(resb)  (compact bf16 in, scattered f32 out)
    mlp3_t<true, false, false, true, false><<<256, 512, 0, stream>>>(
        resb, iw1, ib1, iw2, ib2, iw3, ib3, d_out, nullptr,
        ilist, icnt, nullptr, nullptr, N, ntiles);
}